// Round 2
// baseline (3543.579 us; speedup 1.0000x reference)
//
#include <hip/hip_runtime.h>
#include <hip/hip_bf16.h>
#include <math.h>

#define NN 100000      // nodes
#define NE 1600000     // edges
#define NG 64          // graphs
#define F_IN 5
#define F1 128         // H*HID
#define F2 64          // HID
#define NCLS 4

// ---------- helpers: order-preserving float<->uint encoding for atomicMax ----------
__device__ __forceinline__ unsigned enc_f(float f) {
    unsigned b = __float_as_uint(f);
    return (b & 0x80000000u) ? ~b : (b | 0x80000000u);
}
__device__ __forceinline__ float dec_f(unsigned k) {
    unsigned b = (k & 0x80000000u) ? (k ^ 0x80000000u) : ~k;
    return __uint_as_float(b);
}
#define ENC_NEG_INF 0x007FFFFFu   // enc_f(-inf)

__global__ void k_fill_u32(unsigned* p, unsigned v, int n) {
    int i = blockIdx.x * blockDim.x + threadIdx.x;
    if (i < n) p[i] = v;
}

// ---------- GAT: xw = x @ gat_w ; a_src/a_dst per-node attention logits ----------
__global__ void k_xw(const float* __restrict__ x, const float* __restrict__ gw,
                     const float* __restrict__ aw_src, const float* __restrict__ aw_dst,
                     float* __restrict__ xw, float* __restrict__ a_src, float* __restrict__ a_dst) {
    int n = blockIdx.x;
    int f = threadIdx.x;                 // 128 threads, f = h*64+c
    __shared__ float w[F_IN * F1];
    __shared__ float xs[F_IN];
    for (int i = f; i < F_IN * F1; i += F1) w[i] = gw[i];
    if (f < F_IN) xs[f] = x[n * F_IN + f];
    __syncthreads();
    float acc = 0.f;
#pragma unroll
    for (int i = 0; i < F_IN; i++) acc += xs[i] * w[i * F1 + f];
    xw[n * F1 + f] = acc;
    int h = f >> 6, lane = f & 63;
    float p = acc * aw_src[f];
    float q = acc * aw_dst[f];
#pragma unroll
    for (int off = 32; off > 0; off >>= 1) {
        p += __shfl_down(p, off);
        q += __shfl_down(q, off);
    }
    if (lane == 0) { a_src[n * 2 + h] = p; a_dst[n * 2 + h] = q; }
}

// ---------- edge pass 1: e = leaky_relu(a_src[s]+a_dst[d]); segment max; degree ----------
__global__ void k_edge1(const int* __restrict__ ei, const float* __restrict__ a_src,
                        const float* __restrict__ a_dst, float* __restrict__ ebuf,
                        unsigned* __restrict__ emax, float* __restrict__ deg) {
    int e = blockIdx.x * blockDim.x + threadIdx.x;
    if (e >= NE) return;
    int s = ei[e], d = ei[NE + e];
    float e0 = a_src[s * 2 + 0] + a_dst[d * 2 + 0];
    float e1 = a_src[s * 2 + 1] + a_dst[d * 2 + 1];
    e0 = e0 > 0.f ? e0 : 0.2f * e0;
    e1 = e1 > 0.f ? e1 : 0.2f * e1;
    ebuf[e * 2 + 0] = e0;
    ebuf[e * 2 + 1] = e1;
    atomicMax(&emax[d * 2 + 0], enc_f(e0));
    atomicMax(&emax[d * 2 + 1], enc_f(e1));
    atomicAdd(&deg[d], 1.0f);
}

// decode emax in place (u32 -> float, -inf -> 0)
__global__ void k_emax_fin(unsigned* __restrict__ emax) {
    int i = blockIdx.x * blockDim.x + threadIdx.x;
    if (i >= NN * 2) return;
    float v = dec_f(emax[i]);
    if (!isfinite(v)) v = 0.f;
    ((float*)emax)[i] = v;
}

// ---------- edge pass 2: ex = exp(e - emax[dst]); denom = segsum ----------
__global__ void k_edge2(const int* __restrict__ ei, float* __restrict__ ebuf,
                        const float* __restrict__ emaxf, float* __restrict__ denom) {
    int e = blockIdx.x * blockDim.x + threadIdx.x;
    if (e >= NE) return;
    int d = ei[NE + e];
    float ex0 = expf(ebuf[e * 2 + 0] - emaxf[d * 2 + 0]);
    float ex1 = expf(ebuf[e * 2 + 1] - emaxf[d * 2 + 1]);
    ebuf[e * 2 + 0] = ex0;
    ebuf[e * 2 + 1] = ex1;
    atomicAdd(&denom[d * 2 + 0], ex0);
    atomicAdd(&denom[d * 2 + 1], ex1);
}

// ---------- edge pass 3: h[dst] += xw[src] * alpha  (wave per edge, 128 feats) ----------
__global__ void k_gat_agg(const int* __restrict__ ei, const float* __restrict__ ebuf,
                          const float* __restrict__ denom, const float* __restrict__ xw,
                          float* __restrict__ hbuf) {
    int w = (blockIdx.x * blockDim.x + threadIdx.x) >> 6;
    int lane = threadIdx.x & 63;
    if (w >= NE) return;
    int s = ei[w], d = ei[NE + w];
    float a0 = ebuf[w * 2 + 0] / (denom[d * 2 + 0] + 1e-16f);
    float a1 = ebuf[w * 2 + 1] / (denom[d * 2 + 1] + 1e-16f);
    atomicAdd(&hbuf[d * F1 + lane],      xw[s * F1 + lane] * a0);
    atomicAdd(&hbuf[d * F1 + 64 + lane], xw[s * F1 + 64 + lane] * a1);
}

// ---------- BatchNorm stats: per-feature sum & sumsq ----------
__global__ void k_bn_stats(const float* __restrict__ h, int nfeat, float* __restrict__ sums) {
    int f = threadIdx.x;                       // blockDim.x == nfeat
    int rows = (NN + gridDim.x - 1) / gridDim.x;
    int r0 = blockIdx.x * rows;
    int r1 = min(NN, r0 + rows);
    float s = 0.f, ss = 0.f;
    for (int r = r0; r < r1; r++) {
        float v = h[r * nfeat + f];
        s += v; ss += v * v;
    }
    atomicAdd(&sums[f], s);
    atomicAdd(&sums[nfeat + f], ss);
}

// ---------- BatchNorm apply + ELU, in place ----------
__global__ void k_bn_apply(float* __restrict__ h, const float* __restrict__ sums,
                           const float* __restrict__ g, const float* __restrict__ b,
                           int nfeat, int total) {
    int i = blockIdx.x * blockDim.x + threadIdx.x;
    if (i >= total) return;
    int f = i & (nfeat - 1);
    float m = sums[f] * (1.0f / NN);
    float var = sums[nfeat + f] * (1.0f / NN) - m * m;
    float v = (h[i] - m) * rsqrtf(var + 1e-5f) * g[f] + b[f];
    h[i] = v > 0.f ? v : expm1f(v);
}

// ---------- SAGE aggregate: agg[dst] += h1[src]  (wave per edge, 128 feats) ----------
__global__ void k_sage_agg(const int* __restrict__ ei, const float* __restrict__ h1,
                           float* __restrict__ agg) {
    int w = (blockIdx.x * blockDim.x + threadIdx.x) >> 6;
    int lane = threadIdx.x & 63;
    if (w >= NE) return;
    int s = ei[w], d = ei[NE + w];
    atomicAdd(&agg[d * F1 + lane],      h1[s * F1 + lane]);
    atomicAdd(&agg[d * F1 + 64 + lane], h1[s * F1 + 64 + lane]);
}

// ---------- SAGE GEMM: h2 = (agg/deg) @ wl + bl + h1 @ wr ----------
__global__ void k_sage_gemm(const float* __restrict__ agg, const float* __restrict__ h1,
                            const float* __restrict__ deg, const float* __restrict__ wl,
                            const float* __restrict__ bl, const float* __restrict__ wr,
                            float* __restrict__ h2) {
    __shared__ float swl[F1 * F2];
    __shared__ float swr[F1 * F2];
    __shared__ float rowa[4][F1];
    __shared__ float rowh[4][F1];
    int t = threadIdx.x;
    for (int i = t; i < F1 * F2; i += 256) { swl[i] = wl[i]; swr[i] = wr[i]; }
    int n0 = blockIdx.x * 4;
    for (int i = t; i < 4 * F1; i += 256) {
        int nn = n0 + i / F1;
        if (nn < NN) { rowa[i / F1][i % F1] = agg[nn * F1 + i % F1];
                       rowh[i / F1][i % F1] = h1[nn * F1 + i % F1]; }
    }
    __syncthreads();
    int ln = t >> 6, j = t & 63;
    int n = n0 + ln;
    if (n >= NN) return;
    float inv = 1.0f / fmaxf(deg[n], 1.0f);
    float acc = bl[j];
#pragma unroll 8
    for (int k = 0; k < F1; k++)
        acc += rowa[ln][k] * inv * swl[k * F2 + j] + rowh[ln][k] * swr[k * F2 + j];
    h2[n * F2 + j] = acc;
}

__global__ void k_dinv(const float* __restrict__ deg, float* __restrict__ dinv) {
    int i = blockIdx.x * blockDim.x + threadIdx.x;
    if (i < NN) dinv[i] = rsqrtf(deg[i] + 1.0f);
}

// ---------- GCN GEMM: hw = h2 @ gcn_w ----------
__global__ void k_gcn_gemm(const float* __restrict__ h2, const float* __restrict__ wmat,
                           float* __restrict__ hw) {
    __shared__ float sw[F2 * F2];
    __shared__ float rows[4][F2];
    int t = threadIdx.x;
    for (int i = t; i < F2 * F2; i += 256) sw[i] = wmat[i];
    int n0 = blockIdx.x * 4;
    for (int i = t; i < 4 * F2; i += 256) {
        int nn = n0 + i / F2;
        if (nn < NN) rows[i / F2][i % F2] = h2[nn * F2 + i % F2];
    }
    __syncthreads();
    int ln = t >> 6, j = t & 63;
    int n = n0 + ln;
    if (n >= NN) return;
    float acc = 0.f;
#pragma unroll 8
    for (int k = 0; k < F2; k++) acc += rows[ln][k] * sw[k * F2 + j];
    hw[n * F2 + j] = acc;
}

// ---------- GCN aggregate: h3[dst] += hw[src]*dinv[s]*dinv[d] (wave/edge, 64 feats) ----------
__global__ void k_gcn_agg(const int* __restrict__ ei, const float* __restrict__ hw,
                          const float* __restrict__ dinv, float* __restrict__ h3) {
    int w = (blockIdx.x * blockDim.x + threadIdx.x) >> 6;
    int lane = threadIdx.x & 63;
    if (w >= NE) return;
    int s = ei[w], d = ei[NE + w];
    float c = dinv[s] * dinv[d];
    atomicAdd(&h3[d * F2 + lane], hw[s * F2 + lane] * c);
}

// ---------- GCN self loop + bias ----------
__global__ void k_gcn_self(float* __restrict__ h3, const float* __restrict__ hw,
                           const float* __restrict__ dinv, const float* __restrict__ gb) {
    int i = blockIdx.x * blockDim.x + threadIdx.x;
    if (i >= NN * F2) return;
    int n = i >> 6, f = i & 63;
    float di = dinv[n];
    h3[i] += hw[i] * di * di + gb[f];
}

// ---------- pooling: mean-sum, max, count per graph (wave per node) ----------
__global__ void k_pool(const float* __restrict__ h3, const int* __restrict__ batch,
                       float* __restrict__ psum, unsigned* __restrict__ pmax,
                       float* __restrict__ cnt) {
    int n = (blockIdx.x * blockDim.x + threadIdx.x) >> 6;
    int lane = threadIdx.x & 63;
    if (n >= NN) return;
    int g = batch[n];
    float v = h3[n * F2 + lane];
    atomicAdd(&psum[g * F2 + lane], v);
    atomicMax(&pmax[g * F2 + lane], enc_f(v));
    if (lane == 0) atomicAdd(&cnt[g], 1.0f);
}

// ---------- classifier: out = relu(z@w1+b1)@w2+b2, z = [pmean|pmax] ----------
__global__ void k_cls(const float* __restrict__ psum, const unsigned* __restrict__ pmax,
                      const float* __restrict__ cnt, const float* __restrict__ w1,
                      const float* __restrict__ b1, const float* __restrict__ w2,
                      const float* __restrict__ b2, float* __restrict__ out) {
    int g = blockIdx.x;
    int j = threadIdx.x;  // 64 threads
    __shared__ float z[2 * F2];
    __shared__ float hid[F2];
    float c = fmaxf(cnt[g], 1.0f);
    z[j] = psum[g * F2 + j] / c;
    float mv = dec_f(pmax[g * F2 + j]);
    z[F2 + j] = isfinite(mv) ? mv : 0.f;
    __syncthreads();
    float acc = b1[j];
#pragma unroll 8
    for (int k = 0; k < 2 * F2; k++) acc += z[k] * w1[k * F2 + j];
    hid[j] = fmaxf(acc, 0.f);
    __syncthreads();
    if (j < NCLS) {
        float o = b2[j];
#pragma unroll 8
        for (int k = 0; k < F2; k++) o += hid[k] * w2[k * NCLS + j];
        out[g * NCLS + j] = o;
    }
}

extern "C" void kernel_launch(void* const* d_in, const int* in_sizes, int n_in,
                              void* d_out, int out_size, void* d_ws, size_t ws_size,
                              hipStream_t stream) {
    const float* x       = (const float*)d_in[0];
    const int*   ei      = (const int*)d_in[1];
    const int*   batch   = (const int*)d_in[2];
    const float* gat_w   = (const float*)d_in[3];
    const float* att_src = (const float*)d_in[4];
    const float* att_dst = (const float*)d_in[5];
    // d_in[6] gat_b: cancels inside BN1 (constant shift removed by mean subtraction)
    const float* bn1_g   = (const float*)d_in[7];
    const float* bn1_b   = (const float*)d_in[8];
    const float* sage_wl = (const float*)d_in[9];
    const float* sage_bl = (const float*)d_in[10];
    const float* sage_wr = (const float*)d_in[11];
    const float* bn2_g   = (const float*)d_in[12];
    const float* bn2_b   = (const float*)d_in[13];
    const float* gcn_w   = (const float*)d_in[14];
    const float* gcn_b   = (const float*)d_in[15];
    const float* bn3_g   = (const float*)d_in[16];
    const float* bn3_b   = (const float*)d_in[17];
    const float* w1      = (const float*)d_in[18];
    const float* b1      = (const float*)d_in[19];
    const float* w2      = (const float*)d_in[20];
    const float* b2      = (const float*)d_in[21];
    float* out = (float*)d_out;

    float* ws = (float*)d_ws;
    // workspace layout (floats)
    size_t o_xw   = 0;                       // N*F1  (reused: SAGE agg, then GCN h3)
    size_t o_h1   = o_xw + (size_t)NN * F1;  // N*F1  (GAT out; reused: GCN hw)
    size_t o_ebuf = o_h1 + (size_t)NN * F1;  // E*2
    size_t o_asrc = o_ebuf + (size_t)NE * 2; // N*2
    size_t o_adst = o_asrc + (size_t)NN * 2; // N*2
    size_t o_emax = o_adst + (size_t)NN * 2; // N*2 (u32 then f32)
    size_t o_den  = o_emax + (size_t)NN * 2; // N*2
    size_t o_deg  = o_den  + (size_t)NN * 2; // N
    size_t o_dinv = o_deg  + (size_t)NN;     // N
    size_t o_h2   = o_dinv + (size_t)NN;     // N*F2
    size_t o_sums = o_h2   + (size_t)NN * F2;// 256
    size_t o_psum = o_sums + 256;            // G*F2
    size_t o_pmax = o_psum + (size_t)NG * F2;// G*F2
    size_t o_cnt  = o_pmax + (size_t)NG * F2;// G

    float* xw   = ws + o_xw;
    float* h1   = ws + o_h1;
    float* ebuf = ws + o_ebuf;
    float* asr  = ws + o_asrc;
    float* ads  = ws + o_adst;
    unsigned* emax = (unsigned*)(ws + o_emax);
    float* den  = ws + o_den;
    float* deg  = ws + o_deg;
    float* dinv = ws + o_dinv;
    float* h2   = ws + o_h2;
    float* sums = ws + o_sums;
    float* psum = ws + o_psum;
    unsigned* pmax = (unsigned*)(ws + o_pmax);
    float* cnt  = ws + o_cnt;

    // aliases after reuse
    float* agg = xw;    // after k_gat_agg, xw free -> SAGE agg
    float* hw  = h1;    // after sage_gemm, h1 free -> GCN hw
    float* h3  = xw;    // after sage_gemm, agg free -> GCN out

    // ---- init ----
    k_fill_u32<<<(NN * 2 + 255) / 256, 256, 0, stream>>>(emax, ENC_NEG_INF, NN * 2);
    hipMemsetAsync(den, 0, sizeof(float) * NN * 2, stream);
    hipMemsetAsync(deg, 0, sizeof(float) * NN, stream);

    // ---- GAT ----
    k_xw<<<NN, F1, 0, stream>>>(x, gat_w, att_src, att_dst, xw, asr, ads);
    k_edge1<<<(NE + 255) / 256, 256, 0, stream>>>(ei, asr, ads, ebuf, emax, deg);
    k_emax_fin<<<(NN * 2 + 255) / 256, 256, 0, stream>>>(emax);
    k_edge2<<<(NE + 255) / 256, 256, 0, stream>>>(ei, ebuf, (float*)emax, den);
    hipMemsetAsync(h1, 0, sizeof(float) * (size_t)NN * F1, stream);
    k_gat_agg<<<NE / 4, 256, 0, stream>>>(ei, ebuf, den, xw, h1);
    hipMemsetAsync(sums, 0, sizeof(float) * 256, stream);
    k_bn_stats<<<512, F1, 0, stream>>>(h1, F1, sums);
    k_bn_apply<<<(NN * F1 + 255) / 256, 256, 0, stream>>>(h1, sums, bn1_g, bn1_b, F1, NN * F1);

    // ---- SAGE ----
    hipMemsetAsync(agg, 0, sizeof(float) * (size_t)NN * F1, stream);
    k_sage_agg<<<NE / 4, 256, 0, stream>>>(ei, h1, agg);
    k_sage_gemm<<<(NN + 3) / 4, 256, 0, stream>>>(agg, h1, deg, sage_wl, sage_bl, sage_wr, h2);
    hipMemsetAsync(sums, 0, sizeof(float) * 256, stream);
    k_bn_stats<<<512, F2, 0, stream>>>(h2, F2, sums);
    k_bn_apply<<<(NN * F2 + 255) / 256, 256, 0, stream>>>(h2, sums, bn2_g, bn2_b, F2, NN * F2);

    // ---- GCN ----
    k_dinv<<<(NN + 255) / 256, 256, 0, stream>>>(deg, dinv);
    k_gcn_gemm<<<(NN + 3) / 4, 256, 0, stream>>>(h2, gcn_w, hw);
    hipMemsetAsync(h3, 0, sizeof(float) * (size_t)NN * F2, stream);
    k_gcn_agg<<<NE / 4, 256, 0, stream>>>(ei, hw, dinv, h3);
    k_gcn_self<<<(NN * F2 + 255) / 256, 256, 0, stream>>>(h3, hw, dinv, gcn_b);
    hipMemsetAsync(sums, 0, sizeof(float) * 256, stream);
    k_bn_stats<<<512, F2, 0, stream>>>(h3, F2, sums);
    k_bn_apply<<<(NN * F2 + 255) / 256, 256, 0, stream>>>(h3, sums, bn3_g, bn3_b, F2, NN * F2);

    // ---- pooling + classifier ----
    hipMemsetAsync(psum, 0, sizeof(float) * NG * F2, stream);
    hipMemsetAsync(cnt, 0, sizeof(float) * NG, stream);
    k_fill_u32<<<(NG * F2 + 255) / 256, 256, 0, stream>>>(pmax, ENC_NEG_INF, NG * F2);
    k_pool<<<(NN * 64 + 255) / 256, 256, 0, stream>>>(h3, batch, psum, pmax, cnt);
    k_cls<<<NG, F2, 0, stream>>>(psum, pmax, cnt, w1, b1, w2, b2, out);
}

// Round 7
// 1438.462 us; speedup vs baseline: 2.4635x; 2.4635x over previous
//
#include <hip/hip_runtime.h>
#include <hip/hip_bf16.h>
#include <math.h>

#define NN 100000      // nodes
#define NE 1600000     // edges
#define NG 64          // graphs
#define F_IN 5
#define F1 128         // H*HID
#define F2 64          // HID
#define NCLS 4
#define NB_SCAN ((NN + 255) / 256)   // 391 blocks in scan level 1

// ---------- helpers: order-preserving float<->uint encoding for atomicMax ----------
__device__ __forceinline__ unsigned enc_f(float f) {
    unsigned b = __float_as_uint(f);
    return (b & 0x80000000u) ? ~b : (b | 0x80000000u);
}
__device__ __forceinline__ float dec_f(unsigned k) {
    unsigned b = (k & 0x80000000u) ? (k ^ 0x80000000u) : ~k;
    return __uint_as_float(b);
}
#define ENC_NEG_INF 0x007FFFFFu   // enc_f(-inf)

__global__ void k_fill_u32(unsigned* p, unsigned v, int n) {
    int i = blockIdx.x * blockDim.x + threadIdx.x;
    if (i < n) p[i] = v;
}

// =================== CSR build (sort edges by dst, no payload) ===================
__global__ void k_count(const int* __restrict__ ei, int* __restrict__ degi) {
    int e = blockIdx.x * blockDim.x + threadIdx.x;
    if (e < NE) atomicAdd(&degi[ei[NE + e]], 1);
}

// level-1 scan: per-block exclusive scan of degi into rowptr (local), block sums out
__global__ void k_scan1(const int* __restrict__ degi, int* __restrict__ rowptr,
                        int* __restrict__ bsum) {
    __shared__ int sh[256];
    int i = blockIdx.x * 256 + threadIdx.x;
    int v = (i < NN) ? degi[i] : 0;
    sh[threadIdx.x] = v;
    __syncthreads();
    for (int off = 1; off < 256; off <<= 1) {
        int t = (threadIdx.x >= off) ? sh[threadIdx.x - off] : 0;
        __syncthreads();
        sh[threadIdx.x] += t;
        __syncthreads();
    }
    if (i < NN) rowptr[i] = sh[threadIdx.x] - v;   // exclusive, block-local
    if (threadIdx.x == 255) bsum[blockIdx.x] = sh[255];
}

// level-2 scan: single block, exclusive scan of block sums (nb <= 512)
__global__ void k_scan2(int* __restrict__ bsum, int nb) {
    __shared__ int sh[512];
    int v = (threadIdx.x < nb) ? bsum[threadIdx.x] : 0;
    sh[threadIdx.x] = v;
    __syncthreads();
    for (int off = 1; off < 512; off <<= 1) {
        int t = (threadIdx.x >= off) ? sh[threadIdx.x - off] : 0;
        __syncthreads();
        sh[threadIdx.x] += t;
        __syncthreads();
    }
    if (threadIdx.x < nb) bsum[threadIdx.x] = sh[threadIdx.x] - v;   // exclusive
}

// level-3: add block offsets, init cursor, cap rowptr
__global__ void k_scan3(int* __restrict__ rowptr, int* __restrict__ cursor,
                        const int* __restrict__ bsum) {
    int i = blockIdx.x * 256 + threadIdx.x;
    if (i == 0) rowptr[NN] = NE;
    if (i >= NN) return;
    int r = rowptr[i] + bsum[blockIdx.x];
    rowptr[i] = r;
    cursor[i] = r;
}

__global__ void k_scatter(const int* __restrict__ ei, int* __restrict__ cursor,
                          int* __restrict__ csr_src) {
    int e = blockIdx.x * blockDim.x + threadIdx.x;
    if (e >= NE) return;
    int d = ei[NE + e];
    int pos = atomicAdd(&cursor[d], 1);
    csr_src[pos] = ei[e];
}

// =================== GAT ===================
// xw = x @ gat_w ; a_src/a_dst per-node attention logits
__global__ void k_xw(const float* __restrict__ x, const float* __restrict__ gw,
                     const float* __restrict__ aw_src, const float* __restrict__ aw_dst,
                     float* __restrict__ xw, float* __restrict__ a_src, float* __restrict__ a_dst) {
    int n = blockIdx.x;
    int f = threadIdx.x;                 // 128 threads, f = h*64+c
    __shared__ float w[F_IN * F1];
    __shared__ float xs[F_IN];
    for (int i = f; i < F_IN * F1; i += F1) w[i] = gw[i];
    if (f < F_IN) xs[f] = x[n * F_IN + f];
    __syncthreads();
    float acc = 0.f;
#pragma unroll
    for (int i = 0; i < F_IN; i++) acc += xs[i] * w[i * F1 + f];
    xw[n * F1 + f] = acc;
    int h = f >> 6, lane = f & 63;
    float p = acc * aw_src[f];
    float q = acc * aw_dst[f];
#pragma unroll
    for (int off = 32; off > 0; off >>= 1) {
        p += __shfl_down(p, off);
        q += __shfl_down(q, off);
    }
    if (lane == 0) { a_src[n * 2 + h] = p; a_dst[n * 2 + h] = q; }
}

// gather + online segment-softmax + weighted sum, one wave per dst node, 2 feats/lane
__global__ void k_gat_gather(const int* __restrict__ rowptr, const int* __restrict__ csr_src,
                             const float* __restrict__ a_src, const float* __restrict__ a_dst,
                             const float* __restrict__ xw, float* __restrict__ h1) {
    int n = blockIdx.x * 4 + (threadIdx.x >> 6);
    int lane = threadIdx.x & 63;
    if (n >= NN) return;
    int j0 = rowptr[n], j1 = rowptr[n + 1];
    float ad0 = a_dst[n * 2 + 0], ad1 = a_dst[n * 2 + 1];
    float m0 = -INFINITY, m1 = -INFINITY;
    float s0 = 0.f, s1 = 0.f, acc0 = 0.f, acc1 = 0.f;
    for (int j = j0; j < j1; j++) {
        int s = csr_src[j];
        float l0 = a_src[s * 2 + 0] + ad0;
        float l1 = a_src[s * 2 + 1] + ad1;
        l0 = l0 > 0.f ? l0 : 0.2f * l0;
        l1 = l1 > 0.f ? l1 : 0.2f * l1;
        float nm0 = fmaxf(m0, l0), nm1 = fmaxf(m1, l1);
        float sc0 = expf(m0 - nm0), sc1 = expf(m1 - nm1);
        float w0 = expf(l0 - nm0), w1 = expf(l1 - nm1);
        s0 = s0 * sc0 + w0;
        s1 = s1 * sc1 + w1;
        acc0 = acc0 * sc0 + xw[s * F1 + lane] * w0;
        acc1 = acc1 * sc1 + xw[s * F1 + 64 + lane] * w1;
        m0 = nm0; m1 = nm1;
    }
    h1[n * F1 + lane]      = acc0 / (s0 + 1e-16f);
    h1[n * F1 + 64 + lane] = acc1 / (s1 + 1e-16f);
}

// =================== BatchNorm ===================
__global__ void k_bn_stats(const float* __restrict__ h, int nfeat, float* __restrict__ sums) {
    int f = threadIdx.x;                       // blockDim.x == nfeat
    int rows = (NN + gridDim.x - 1) / gridDim.x;
    int r0 = blockIdx.x * rows;
    int r1 = min(NN, r0 + rows);
    float s = 0.f, ss = 0.f;
    for (int r = r0; r < r1; r++) {
        float v = h[r * nfeat + f];
        s += v; ss += v * v;
    }
    atomicAdd(&sums[f], s);
    atomicAdd(&sums[nfeat + f], ss);
}

__global__ void k_bn_apply(float* __restrict__ h, const float* __restrict__ sums,
                           const float* __restrict__ g, const float* __restrict__ b,
                           int nfeat, int total) {
    int i = blockIdx.x * blockDim.x + threadIdx.x;
    if (i >= total) return;
    int f = i & (nfeat - 1);
    float m = sums[f] * (1.0f / NN);
    float var = sums[nfeat + f] * (1.0f / NN) - m * m;
    float v = (h[i] - m) * rsqrtf(var + 1e-5f) * g[f] + b[f];
    h[i] = v > 0.f ? v : expm1f(v);
}

// =================== SAGE ===================
// mean-gather, one wave per dst node, 2 feats/lane
__global__ void k_sage_gather(const int* __restrict__ rowptr, const int* __restrict__ csr_src,
                              const float* __restrict__ h1, float* __restrict__ agg) {
    int n = blockIdx.x * 4 + (threadIdx.x >> 6);
    int lane = threadIdx.x & 63;
    if (n >= NN) return;
    int j0 = rowptr[n], j1 = rowptr[n + 1];
    float a0 = 0.f, a1 = 0.f;
    for (int j = j0; j < j1; j++) {
        int s = csr_src[j];
        a0 += h1[s * F1 + lane];
        a1 += h1[s * F1 + 64 + lane];
    }
    float inv = 1.0f / fmaxf((float)(j1 - j0), 1.0f);
    agg[n * F1 + lane]      = a0 * inv;
    agg[n * F1 + 64 + lane] = a1 * inv;
}

// h2 = agg @ wl + bl + h1 @ wr   (agg already mean-normalized)
__global__ void k_sage_gemm(const float* __restrict__ agg, const float* __restrict__ h1,
                            const float* __restrict__ wl, const float* __restrict__ bl,
                            const float* __restrict__ wr, float* __restrict__ h2) {
    __shared__ float swl[F1 * F2];
    __shared__ float swr[F1 * F2];
    __shared__ float rowa[4][F1];
    __shared__ float rowh[4][F1];
    int t = threadIdx.x;
    for (int i = t; i < F1 * F2; i += 256) { swl[i] = wl[i]; swr[i] = wr[i]; }
    int n0 = blockIdx.x * 4;
    for (int i = t; i < 4 * F1; i += 256) {
        int nn = n0 + i / F1;
        if (nn < NN) { rowa[i / F1][i % F1] = agg[nn * F1 + i % F1];
                       rowh[i / F1][i % F1] = h1[nn * F1 + i % F1]; }
    }
    __syncthreads();
    int ln = t >> 6, j = t & 63;
    int n = n0 + ln;
    if (n >= NN) return;
    float acc = bl[j];
#pragma unroll 8
    for (int k = 0; k < F1; k++)
        acc += rowa[ln][k] * swl[k * F2 + j] + rowh[ln][k] * swr[k * F2 + j];
    h2[n * F2 + j] = acc;
}

__global__ void k_dinv(const int* __restrict__ degi, float* __restrict__ dinv) {
    int i = blockIdx.x * blockDim.x + threadIdx.x;
    if (i < NN) dinv[i] = rsqrtf((float)degi[i] + 1.0f);
}

// =================== GCN ===================
__global__ void k_gcn_gemm(const float* __restrict__ h2, const float* __restrict__ wmat,
                           float* __restrict__ hw) {
    __shared__ float sw[F2 * F2];
    __shared__ float rows[4][F2];
    int t = threadIdx.x;
    for (int i = t; i < F2 * F2; i += 256) sw[i] = wmat[i];
    int n0 = blockIdx.x * 4;
    for (int i = t; i < 4 * F2; i += 256) {
        int nn = n0 + i / F2;
        if (nn < NN) rows[i / F2][i % F2] = h2[nn * F2 + i % F2];
    }
    __syncthreads();
    int ln = t >> 6, j = t & 63;
    int n = n0 + ln;
    if (n >= NN) return;
    float acc = 0.f;
#pragma unroll 8
    for (int k = 0; k < F2; k++) acc += rows[ln][k] * sw[k * F2 + j];
    hw[n * F2 + j] = acc;
}

// gather + self-loop + bias fused, one wave per dst node, 1 feat/lane
__global__ void k_gcn_gather(const int* __restrict__ rowptr, const int* __restrict__ csr_src,
                             const float* __restrict__ hw, const float* __restrict__ dinv,
                             const float* __restrict__ gb, float* __restrict__ h3) {
    int n = blockIdx.x * 4 + (threadIdx.x >> 6);
    int lane = threadIdx.x & 63;
    if (n >= NN) return;
    int j0 = rowptr[n], j1 = rowptr[n + 1];
    float acc = 0.f;
    for (int j = j0; j < j1; j++) {
        int s = csr_src[j];
        acc += hw[s * F2 + lane] * dinv[s];
    }
    float di = dinv[n];
    h3[n * F2 + lane] = acc * di + hw[n * F2 + lane] * di * di + gb[lane];
}

// =================== fused BN3-apply + ELU + segmented pool ===================
// batch[] is sorted, so graph segments are contiguous: register-accumulate per
// segment run, flush one atomic per (block x boundary). h3 post-BN never stored.
__global__ void k_bn3_pool(const float* __restrict__ h3raw, const float* __restrict__ sums,
                           const float* __restrict__ g3, const float* __restrict__ b3,
                           const int* __restrict__ batch, float* __restrict__ psum,
                           unsigned* __restrict__ pmax, float* __restrict__ cnt) {
    int lane = threadIdx.x;   // 64 threads = one wave, lane = feature
    int rows = (NN + gridDim.x - 1) / gridDim.x;
    int r0 = blockIdx.x * rows;
    int r1 = min(NN, r0 + rows);
    if (r0 >= r1) return;
    float m = sums[lane] * (1.0f / NN);
    float var = sums[F2 + lane] * (1.0f / NN) - m * m;
    float sc = rsqrtf(var + 1e-5f) * g3[lane];
    float bb = b3[lane];
    int curg = batch[r0];
    float ls = 0.f, lm = -INFINITY;
    int run = 0;
    for (int r = r0; r < r1; r++) {
        int gg = batch[r];
        if (gg != curg) {
            atomicAdd(&psum[curg * F2 + lane], ls);
            atomicMax(&pmax[curg * F2 + lane], enc_f(lm));
            if (lane == 0) atomicAdd(&cnt[curg], (float)run);
            curg = gg; ls = 0.f; lm = -INFINITY; run = 0;
        }
        float v = (h3raw[r * F2 + lane] - m) * sc + bb;
        v = v > 0.f ? v : expm1f(v);
        ls += v; lm = fmaxf(lm, v); run++;
    }
    atomicAdd(&psum[curg * F2 + lane], ls);
    atomicMax(&pmax[curg * F2 + lane], enc_f(lm));
    if (lane == 0) atomicAdd(&cnt[curg], (float)run);
}

// =================== classifier ===================
__global__ void k_cls(const float* __restrict__ psum, const unsigned* __restrict__ pmax,
                      const float* __restrict__ cnt, const float* __restrict__ w1,
                      const float* __restrict__ b1, const float* __restrict__ w2,
                      const float* __restrict__ b2, float* __restrict__ out) {
    int g = blockIdx.x;
    int j = threadIdx.x;  // 64 threads
    __shared__ float z[2 * F2];
    __shared__ float hid[F2];
    float c = fmaxf(cnt[g], 1.0f);
    z[j] = psum[g * F2 + j] / c;
    float mv = dec_f(pmax[g * F2 + j]);
    z[F2 + j] = isfinite(mv) ? mv : 0.f;
    __syncthreads();
    float acc = b1[j];
#pragma unroll 8
    for (int k = 0; k < 2 * F2; k++) acc += z[k] * w1[k * F2 + j];
    hid[j] = fmaxf(acc, 0.f);
    __syncthreads();
    if (j < NCLS) {
        float o = b2[j];
#pragma unroll 8
        for (int k = 0; k < F2; k++) o += hid[k] * w2[k * NCLS + j];
        out[g * NCLS + j] = o;
    }
}

extern "C" void kernel_launch(void* const* d_in, const int* in_sizes, int n_in,
                              void* d_out, int out_size, void* d_ws, size_t ws_size,
                              hipStream_t stream) {
    const float* x       = (const float*)d_in[0];
    const int*   ei      = (const int*)d_in[1];
    const int*   batch   = (const int*)d_in[2];
    const float* gat_w   = (const float*)d_in[3];
    const float* att_src = (const float*)d_in[4];
    const float* att_dst = (const float*)d_in[5];
    // d_in[6] gat_b: cancels inside BN1 (constant shift removed by mean subtraction)
    const float* bn1_g   = (const float*)d_in[7];
    const float* bn1_b   = (const float*)d_in[8];
    const float* sage_wl = (const float*)d_in[9];
    const float* sage_bl = (const float*)d_in[10];
    const float* sage_wr = (const float*)d_in[11];
    const float* bn2_g   = (const float*)d_in[12];
    const float* bn2_b   = (const float*)d_in[13];
    const float* gcn_w   = (const float*)d_in[14];
    const float* gcn_b   = (const float*)d_in[15];
    const float* bn3_g   = (const float*)d_in[16];
    const float* bn3_b   = (const float*)d_in[17];
    const float* w1      = (const float*)d_in[18];
    const float* b1      = (const float*)d_in[19];
    const float* w2      = (const float*)d_in[20];
    const float* b2      = (const float*)d_in[21];
    float* out = (float*)d_out;

    float* ws = (float*)d_ws;
    // workspace layout (4-byte units)
    size_t o_A    = 0;                        // N*F1: xw -> SAGE agg -> {hw | h3}
    size_t o_h1   = o_A   + (size_t)NN * F1;  // N*F1: GAT output (post-BN1)
    size_t o_h2   = o_h1  + (size_t)NN * F1;  // N*F2
    size_t o_csr  = o_h2  + (size_t)NN * F2;  // E ints (csr_src)
    size_t o_rp   = o_csr + (size_t)NE;       // N+1 ints (rowptr)
    size_t o_cur  = o_rp  + (size_t)(NN + 1); // N ints (cursor)
    size_t o_deg  = o_cur + (size_t)NN;       // N ints (degi)
    size_t o_bs   = o_deg + (size_t)NN;       // 512 ints (block sums)
    size_t o_asrc = o_bs  + 512;              // N*2
    size_t o_adst = o_asrc + (size_t)NN * 2;  // N*2
    size_t o_dinv = o_adst + (size_t)NN * 2;  // N
    size_t o_sums = o_dinv + (size_t)NN;      // 256
    size_t o_psum = o_sums + 256;             // G*F2
    size_t o_pmax = o_psum + (size_t)NG * F2; // G*F2
    size_t o_cnt  = o_pmax + (size_t)NG * F2; // G

    float* A    = ws + o_A;
    float* h1   = ws + o_h1;
    float* h2   = ws + o_h2;
    int* csr_src = (int*)(ws + o_csr);
    int* rowptr  = (int*)(ws + o_rp);
    int* cursor  = (int*)(ws + o_cur);
    int* degi    = (int*)(ws + o_deg);
    int* bsum    = (int*)(ws + o_bs);
    float* asr  = ws + o_asrc;
    float* ads  = ws + o_adst;
    float* dinv = ws + o_dinv;
    float* sums = ws + o_sums;
    float* psum = ws + o_psum;
    unsigned* pmax = (unsigned*)(ws + o_pmax);
    float* cnt  = ws + o_cnt;

    // region-A role aliases
    float* xw  = A;                        // GAT
    float* agg = A;                        // SAGE (xw dead)
    float* hw  = A;                        // GCN gemm out (agg dead), N*F2
    float* h3  = A + (size_t)NN * F2;      // GCN gather out, N*F2

    // ---- CSR build ----
    hipMemsetAsync(degi, 0, sizeof(int) * NN, stream);
    k_count<<<(NE + 255) / 256, 256, 0, stream>>>(ei, degi);
    k_scan1<<<NB_SCAN, 256, 0, stream>>>(degi, rowptr, bsum);
    k_scan2<<<1, 512, 0, stream>>>(bsum, NB_SCAN);
    k_scan3<<<NB_SCAN, 256, 0, stream>>>(rowptr, cursor, bsum);
    k_scatter<<<(NE + 255) / 256, 256, 0, stream>>>(ei, cursor, csr_src);

    // ---- GAT ----
    k_xw<<<NN, F1, 0, stream>>>(x, gat_w, att_src, att_dst, xw, asr, ads);
    k_gat_gather<<<(NN + 3) / 4, 256, 0, stream>>>(rowptr, csr_src, asr, ads, xw, h1);
    hipMemsetAsync(sums, 0, sizeof(float) * 256, stream);
    k_bn_stats<<<512, F1, 0, stream>>>(h1, F1, sums);
    k_bn_apply<<<(NN * F1 + 255) / 256, 256, 0, stream>>>(h1, sums, bn1_g, bn1_b, F1, NN * F1);

    // ---- SAGE ----
    k_sage_gather<<<(NN + 3) / 4, 256, 0, stream>>>(rowptr, csr_src, h1, agg);
    k_sage_gemm<<<(NN + 3) / 4, 256, 0, stream>>>(agg, h1, sage_wl, sage_bl, sage_wr, h2);
    hipMemsetAsync(sums, 0, sizeof(float) * 256, stream);
    k_bn_stats<<<512, F2, 0, stream>>>(h2, F2, sums);
    k_bn_apply<<<(NN * F2 + 255) / 256, 256, 0, stream>>>(h2, sums, bn2_g, bn2_b, F2, NN * F2);

    // ---- GCN ----
    k_dinv<<<(NN + 255) / 256, 256, 0, stream>>>(degi, dinv);
    k_gcn_gemm<<<(NN + 3) / 4, 256, 0, stream>>>(h2, gcn_w, hw);
    k_gcn_gather<<<(NN + 3) / 4, 256, 0, stream>>>(rowptr, csr_src, hw, dinv, gcn_b, h3);
    hipMemsetAsync(sums, 0, sizeof(float) * 256, stream);
    k_bn_stats<<<512, F2, 0, stream>>>(h3, F2, sums);

    // ---- fused BN3 + ELU + pooling, then classifier ----
    hipMemsetAsync(psum, 0, sizeof(float) * NG * F2, stream);
    hipMemsetAsync(cnt, 0, sizeof(float) * NG, stream);
    k_fill_u32<<<(NG * F2 + 255) / 256, 256, 0, stream>>>(pmax, ENC_NEG_INF, NG * F2);
    k_bn3_pool<<<512, F2, 0, stream>>>(h3, sums, bn3_g, bn3_b, batch, psum, pmax, cnt);
    k_cls<<<NG, F2, 0, stream>>>(psum, pmax, cnt, w1, b1, w2, b2, out);
}

// Round 8
// 1289.819 us; speedup vs baseline: 2.7473x; 1.1152x over previous
//
#include <hip/hip_runtime.h>
#include <hip/hip_bf16.h>
#include <math.h>

#define NN 100000      // nodes
#define NE 1600000     // edges
#define NG 64          // graphs
#define F_IN 5
#define F1 128         // H*HID
#define F2 64          // HID
#define NCLS 4
#define NB_SCAN ((NN + 255) / 256)   // 391 blocks in scan level 1
#define GROWS 32                     // rows per block in register-blocked GEMMs (NN % 32 == 0)

// ---------- helpers: order-preserving float<->uint encoding for atomicMax ----------
__device__ __forceinline__ unsigned enc_f(float f) {
    unsigned b = __float_as_uint(f);
    return (b & 0x80000000u) ? ~b : (b | 0x80000000u);
}
__device__ __forceinline__ float dec_f(unsigned k) {
    unsigned b = (k & 0x80000000u) ? (k ^ 0x80000000u) : ~k;
    return __uint_as_float(b);
}
#define ENC_NEG_INF 0x007FFFFFu   // enc_f(-inf)

__global__ void k_fill_u32(unsigned* p, unsigned v, int n) {
    int i = blockIdx.x * blockDim.x + threadIdx.x;
    if (i < n) p[i] = v;
}

// =================== CSR build (sort edges by dst, no payload) ===================
__global__ void k_count(const int* __restrict__ ei, int* __restrict__ degi) {
    int e = blockIdx.x * blockDim.x + threadIdx.x;
    if (e < NE) atomicAdd(&degi[ei[NE + e]], 1);
}

__global__ void k_scan1(const int* __restrict__ degi, int* __restrict__ rowptr,
                        int* __restrict__ bsum) {
    __shared__ int sh[256];
    int i = blockIdx.x * 256 + threadIdx.x;
    int v = (i < NN) ? degi[i] : 0;
    sh[threadIdx.x] = v;
    __syncthreads();
    for (int off = 1; off < 256; off <<= 1) {
        int t = (threadIdx.x >= off) ? sh[threadIdx.x - off] : 0;
        __syncthreads();
        sh[threadIdx.x] += t;
        __syncthreads();
    }
    if (i < NN) rowptr[i] = sh[threadIdx.x] - v;   // exclusive, block-local
    if (threadIdx.x == 255) bsum[blockIdx.x] = sh[255];
}

__global__ void k_scan2(int* __restrict__ bsum, int nb) {
    __shared__ int sh[512];
    int v = (threadIdx.x < nb) ? bsum[threadIdx.x] : 0;
    sh[threadIdx.x] = v;
    __syncthreads();
    for (int off = 1; off < 512; off <<= 1) {
        int t = (threadIdx.x >= off) ? sh[threadIdx.x - off] : 0;
        __syncthreads();
        sh[threadIdx.x] += t;
        __syncthreads();
    }
    if (threadIdx.x < nb) bsum[threadIdx.x] = sh[threadIdx.x] - v;   // exclusive
}

__global__ void k_scan3(int* __restrict__ rowptr, int* __restrict__ cursor,
                        const int* __restrict__ bsum) {
    int i = blockIdx.x * 256 + threadIdx.x;
    if (i == 0) rowptr[NN] = NE;
    if (i >= NN) return;
    int r = rowptr[i] + bsum[blockIdx.x];
    rowptr[i] = r;
    cursor[i] = r;
}

__global__ void k_scatter(const int* __restrict__ ei, int* __restrict__ cursor,
                          int* __restrict__ csr_src) {
    int e = blockIdx.x * blockDim.x + threadIdx.x;
    if (e >= NE) return;
    int d = ei[NE + e];
    int pos = atomicAdd(&cursor[d], 1);
    csr_src[pos] = ei[e];
}

// =================== GAT ===================
__global__ void k_xw(const float* __restrict__ x, const float* __restrict__ gw,
                     const float* __restrict__ aw_src, const float* __restrict__ aw_dst,
                     float* __restrict__ xw, float* __restrict__ a_src, float* __restrict__ a_dst) {
    int n = blockIdx.x;
    int f = threadIdx.x;                 // 128 threads, f = h*64+c
    __shared__ float w[F_IN * F1];
    __shared__ float xs[F_IN];
    for (int i = f; i < F_IN * F1; i += F1) w[i] = gw[i];
    if (f < F_IN) xs[f] = x[n * F_IN + f];
    __syncthreads();
    float acc = 0.f;
#pragma unroll
    for (int i = 0; i < F_IN; i++) acc += xs[i] * w[i * F1 + f];
    xw[n * F1 + f] = acc;
    int h = f >> 6, lane = f & 63;
    float p = acc * aw_src[f];
    float q = acc * aw_dst[f];
#pragma unroll
    for (int off = 32; off > 0; off >>= 1) {
        p += __shfl_down(p, off);
        q += __shfl_down(q, off);
    }
    if (lane == 0) { a_src[n * 2 + h] = p; a_dst[n * 2 + h] = q; }
}

// gather + online segment-softmax + weighted sum, one wave per dst node, 2 feats/lane
__global__ void k_gat_gather(const int* __restrict__ rowptr, const int* __restrict__ csr_src,
                             const float* __restrict__ a_src, const float* __restrict__ a_dst,
                             const float* __restrict__ xw, float* __restrict__ h1) {
    int n = blockIdx.x * 4 + (threadIdx.x >> 6);
    int lane = threadIdx.x & 63;
    if (n >= NN) return;
    int j0 = rowptr[n], j1 = rowptr[n + 1];
    float ad0 = a_dst[n * 2 + 0], ad1 = a_dst[n * 2 + 1];
    float m0 = -INFINITY, m1 = -INFINITY;
    float s0 = 0.f, s1 = 0.f, acc0 = 0.f, acc1 = 0.f;
    for (int j = j0; j < j1; j++) {
        int s = csr_src[j];
        float l0 = a_src[s * 2 + 0] + ad0;
        float l1 = a_src[s * 2 + 1] + ad1;
        l0 = l0 > 0.f ? l0 : 0.2f * l0;
        l1 = l1 > 0.f ? l1 : 0.2f * l1;
        float nm0 = fmaxf(m0, l0), nm1 = fmaxf(m1, l1);
        float sc0 = expf(m0 - nm0), sc1 = expf(m1 - nm1);
        float w0 = expf(l0 - nm0), w1 = expf(l1 - nm1);
        s0 = s0 * sc0 + w0;
        s1 = s1 * sc1 + w1;
        acc0 = acc0 * sc0 + xw[s * F1 + lane] * w0;
        acc1 = acc1 * sc1 + xw[s * F1 + 64 + lane] * w1;
        m0 = nm0; m1 = nm1;
    }
    h1[n * F1 + lane]      = acc0 / (s0 + 1e-16f);
    h1[n * F1 + 64 + lane] = acc1 / (s1 + 1e-16f);
}

// =================== BatchNorm ===================
__global__ void k_bn_stats(const float* __restrict__ h, int nfeat, float* __restrict__ sums) {
    int f = threadIdx.x;                       // blockDim.x == nfeat
    int rows = (NN + gridDim.x - 1) / gridDim.x;
    int r0 = blockIdx.x * rows;
    int r1 = min(NN, r0 + rows);
    float s = 0.f, ss = 0.f;
    for (int r = r0; r < r1; r++) {
        float v = h[r * nfeat + f];
        s += v; ss += v * v;
    }
    atomicAdd(&sums[f], s);
    atomicAdd(&sums[nfeat + f], ss);
}

__global__ void k_bn_apply(float* __restrict__ h, const float* __restrict__ sums,
                           const float* __restrict__ g, const float* __restrict__ b,
                           int nfeat, int total) {
    int i = blockIdx.x * blockDim.x + threadIdx.x;
    if (i >= total) return;
    int f = i & (nfeat - 1);
    float m = sums[f] * (1.0f / NN);
    float var = sums[nfeat + f] * (1.0f / NN) - m * m;
    float v = (h[i] - m) * rsqrtf(var + 1e-5f) * g[f] + b[f];
    h[i] = v > 0.f ? v : expm1f(v);
}

// =================== SAGE (GEMM pulled through the gather via linearity) ===================
// u = h1 @ wl ; v = h1 @ wr  — register-blocked dual GEMM, one pass over h1.
// 256 thr = 4 waves; wave w owns 8 rows; lane j = output column. 16 acc regs/thread.
// Weights staged once per block in LDS [k][j] (consecutive-lane reads: conflict-free).
__global__ void k_sage_dualgemm(const float* __restrict__ h1,
                                const float* __restrict__ wl, const float* __restrict__ wr,
                                float* __restrict__ u, float* __restrict__ v) {
    __shared__ float swl[F1 * F2];   // 32 KB
    __shared__ float swr[F1 * F2];   // 32 KB
    int t = threadIdx.x;
    const float4* wl4 = (const float4*)wl;
    const float4* wr4 = (const float4*)wr;
    float4* swl4 = (float4*)swl;
    float4* swr4 = (float4*)swr;
    for (int i = t; i < F1 * F2 / 4; i += 256) { swl4[i] = wl4[i]; swr4[i] = wr4[i]; }
    __syncthreads();
    int w = t >> 6, j = t & 63;
    int row0 = blockIdx.x * GROWS + w * 8;
    float accu[8] = {0.f, 0.f, 0.f, 0.f, 0.f, 0.f, 0.f, 0.f};
    float accv[8] = {0.f, 0.f, 0.f, 0.f, 0.f, 0.f, 0.f, 0.f};
    for (int k = 0; k < F1; k += 4) {
        float4 a[8];
#pragma unroll
        for (int r = 0; r < 8; r++)
            a[r] = *(const float4*)&h1[(size_t)(row0 + r) * F1 + k];
#pragma unroll
        for (int kk = 0; kk < 4; kk++) {
            float wlj = swl[(k + kk) * F2 + j];
            float wrj = swr[(k + kk) * F2 + j];
#pragma unroll
            for (int r = 0; r < 8; r++) {
                float av = (&a[r].x)[kk];
                accu[r] += av * wlj;
                accv[r] += av * wrj;
            }
        }
    }
#pragma unroll
    for (int r = 0; r < 8; r++) {
        u[(size_t)(row0 + r) * F2 + j] = accu[r];
        v[(size_t)(row0 + r) * F2 + j] = accv[r];
    }
}

// h2[n] = mean-gather(u) + v[n] + bl   (64-wide gather: 256 B/edge, half of before)
__global__ void k_sage_gather2(const int* __restrict__ rowptr, const int* __restrict__ csr_src,
                               const float* __restrict__ u, const float* __restrict__ v,
                               const float* __restrict__ bl, float* __restrict__ h2) {
    int n = blockIdx.x * 4 + (threadIdx.x >> 6);
    int lane = threadIdx.x & 63;
    if (n >= NN) return;
    int j0 = rowptr[n], j1 = rowptr[n + 1];
    float a = 0.f;
    for (int j = j0; j < j1; j++) {
        int s = csr_src[j];
        a += u[(size_t)s * F2 + lane];
    }
    float inv = 1.0f / fmaxf((float)(j1 - j0), 1.0f);
    h2[(size_t)n * F2 + lane] = a * inv + v[(size_t)n * F2 + lane] + bl[lane];
}

__global__ void k_dinv(const int* __restrict__ degi, float* __restrict__ dinv) {
    int i = blockIdx.x * blockDim.x + threadIdx.x;
    if (i < NN) dinv[i] = rsqrtf((float)degi[i] + 1.0f);
}

// =================== GCN ===================
// hw = h2 @ gcn_w — same register-blocked structure (K=64, 16 KB LDS).
__global__ void k_gcn_gemm(const float* __restrict__ h2, const float* __restrict__ wmat,
                           float* __restrict__ hw) {
    __shared__ float sw[F2 * F2];    // 16 KB
    int t = threadIdx.x;
    const float4* w4 = (const float4*)wmat;
    float4* sw4 = (float4*)sw;
    for (int i = t; i < F2 * F2 / 4; i += 256) sw4[i] = w4[i];
    __syncthreads();
    int w = t >> 6, j = t & 63;
    int row0 = blockIdx.x * GROWS + w * 8;
    float acc[8] = {0.f, 0.f, 0.f, 0.f, 0.f, 0.f, 0.f, 0.f};
    for (int k = 0; k < F2; k += 4) {
        float4 a[8];
#pragma unroll
        for (int r = 0; r < 8; r++)
            a[r] = *(const float4*)&h2[(size_t)(row0 + r) * F2 + k];
#pragma unroll
        for (int kk = 0; kk < 4; kk++) {
            float wkj = sw[(k + kk) * F2 + j];
#pragma unroll
            for (int r = 0; r < 8; r++)
                acc[r] += (&a[r].x)[kk] * wkj;
        }
    }
#pragma unroll
    for (int r = 0; r < 8; r++)
        hw[(size_t)(row0 + r) * F2 + j] = acc[r];
}

// gather + self-loop + bias fused, one wave per dst node, 1 feat/lane
__global__ void k_gcn_gather(const int* __restrict__ rowptr, const int* __restrict__ csr_src,
                             const float* __restrict__ hw, const float* __restrict__ dinv,
                             const float* __restrict__ gb, float* __restrict__ h3) {
    int n = blockIdx.x * 4 + (threadIdx.x >> 6);
    int lane = threadIdx.x & 63;
    if (n >= NN) return;
    int j0 = rowptr[n], j1 = rowptr[n + 1];
    float acc = 0.f;
    for (int j = j0; j < j1; j++) {
        int s = csr_src[j];
        acc += hw[s * F2 + lane] * dinv[s];
    }
    float di = dinv[n];
    h3[n * F2 + lane] = acc * di + hw[n * F2 + lane] * di * di + gb[lane];
}

// =================== fused BN3-apply + ELU + segmented pool ===================
__global__ void k_bn3_pool(const float* __restrict__ h3raw, const float* __restrict__ sums,
                           const float* __restrict__ g3, const float* __restrict__ b3,
                           const int* __restrict__ batch, float* __restrict__ psum,
                           unsigned* __restrict__ pmax, float* __restrict__ cnt) {
    int lane = threadIdx.x;   // 64 threads = one wave, lane = feature
    int rows = (NN + gridDim.x - 1) / gridDim.x;
    int r0 = blockIdx.x * rows;
    int r1 = min(NN, r0 + rows);
    if (r0 >= r1) return;
    float m = sums[lane] * (1.0f / NN);
    float var = sums[F2 + lane] * (1.0f / NN) - m * m;
    float sc = rsqrtf(var + 1e-5f) * g3[lane];
    float bb = b3[lane];
    int curg = batch[r0];
    float ls = 0.f, lm = -INFINITY;
    int run = 0;
    for (int r = r0; r < r1; r++) {
        int gg = batch[r];
        if (gg != curg) {
            atomicAdd(&psum[curg * F2 + lane], ls);
            atomicMax(&pmax[curg * F2 + lane], enc_f(lm));
            if (lane == 0) atomicAdd(&cnt[curg], (float)run);
            curg = gg; ls = 0.f; lm = -INFINITY; run = 0;
        }
        float v = (h3raw[r * F2 + lane] - m) * sc + bb;
        v = v > 0.f ? v : expm1f(v);
        ls += v; lm = fmaxf(lm, v); run++;
    }
    atomicAdd(&psum[curg * F2 + lane], ls);
    atomicMax(&pmax[curg * F2 + lane], enc_f(lm));
    if (lane == 0) atomicAdd(&cnt[curg], (float)run);
}

// =================== classifier ===================
__global__ void k_cls(const float* __restrict__ psum, const unsigned* __restrict__ pmax,
                      const float* __restrict__ cnt, const float* __restrict__ w1,
                      const float* __restrict__ b1, const float* __restrict__ w2,
                      const float* __restrict__ b2, float* __restrict__ out) {
    int g = blockIdx.x;
    int j = threadIdx.x;  // 64 threads
    __shared__ float z[2 * F2];
    __shared__ float hid[F2];
    float c = fmaxf(cnt[g], 1.0f);
    z[j] = psum[g * F2 + j] / c;
    float mv = dec_f(pmax[g * F2 + j]);
    z[F2 + j] = isfinite(mv) ? mv : 0.f;
    __syncthreads();
    float acc = b1[j];
#pragma unroll 8
    for (int k = 0; k < 2 * F2; k++) acc += z[k] * w1[k * F2 + j];
    hid[j] = fmaxf(acc, 0.f);
    __syncthreads();
    if (j < NCLS) {
        float o = b2[j];
#pragma unroll 8
        for (int k = 0; k < F2; k++) o += hid[k] * w2[k * NCLS + j];
        out[g * NCLS + j] = o;
    }
}

extern "C" void kernel_launch(void* const* d_in, const int* in_sizes, int n_in,
                              void* d_out, int out_size, void* d_ws, size_t ws_size,
                              hipStream_t stream) {
    const float* x       = (const float*)d_in[0];
    const int*   ei      = (const int*)d_in[1];
    const int*   batch   = (const int*)d_in[2];
    const float* gat_w   = (const float*)d_in[3];
    const float* att_src = (const float*)d_in[4];
    const float* att_dst = (const float*)d_in[5];
    // d_in[6] gat_b: cancels inside BN1 (constant shift removed by mean subtraction)
    const float* bn1_g   = (const float*)d_in[7];
    const float* bn1_b   = (const float*)d_in[8];
    const float* sage_wl = (const float*)d_in[9];
    const float* sage_bl = (const float*)d_in[10];
    const float* sage_wr = (const float*)d_in[11];
    const float* bn2_g   = (const float*)d_in[12];
    const float* bn2_b   = (const float*)d_in[13];
    const float* gcn_w   = (const float*)d_in[14];
    const float* gcn_b   = (const float*)d_in[15];
    const float* bn3_g   = (const float*)d_in[16];
    const float* bn3_b   = (const float*)d_in[17];
    const float* w1      = (const float*)d_in[18];
    const float* b1      = (const float*)d_in[19];
    const float* w2      = (const float*)d_in[20];
    const float* b2      = (const float*)d_in[21];
    float* out = (float*)d_out;

    float* ws = (float*)d_ws;
    // workspace layout (4-byte units)
    size_t o_A    = 0;                        // N*F1: xw -> {u|v} -> {hw | h3}
    size_t o_h1   = o_A   + (size_t)NN * F1;  // N*F1: GAT output (post-BN1)
    size_t o_h2   = o_h1  + (size_t)NN * F1;  // N*F2
    size_t o_csr  = o_h2  + (size_t)NN * F2;  // E ints (csr_src)
    size_t o_rp   = o_csr + (size_t)NE;       // N+1 ints (rowptr)
    size_t o_cur  = o_rp  + (size_t)(NN + 1); // N ints (cursor)
    size_t o_deg  = o_cur + (size_t)NN;       // N ints (degi)
    size_t o_bs   = o_deg + (size_t)NN;       // 512 ints (block sums)
    size_t o_asrc = o_bs  + 512;              // N*2
    size_t o_adst = o_asrc + (size_t)NN * 2;  // N*2
    size_t o_dinv = o_adst + (size_t)NN * 2;  // N
    size_t o_sums = o_dinv + (size_t)NN;      // 256
    size_t o_psum = o_sums + 256;             // G*F2
    size_t o_pmax = o_psum + (size_t)NG * F2; // G*F2
    size_t o_cnt  = o_pmax + (size_t)NG * F2; // G

    float* A    = ws + o_A;
    float* h1   = ws + o_h1;
    float* h2   = ws + o_h2;
    int* csr_src = (int*)(ws + o_csr);
    int* rowptr  = (int*)(ws + o_rp);
    int* cursor  = (int*)(ws + o_cur);
    int* degi    = (int*)(ws + o_deg);
    int* bsum    = (int*)(ws + o_bs);
    float* asr  = ws + o_asrc;
    float* ads  = ws + o_adst;
    float* dinv = ws + o_dinv;
    float* sums = ws + o_sums;
    float* psum = ws + o_psum;
    unsigned* pmax = (unsigned*)(ws + o_pmax);
    float* cnt  = ws + o_cnt;

    // region-A role aliases (lifetimes disjoint)
    float* xw  = A;                        // GAT
    float* u   = A;                        // SAGE u = h1@wl (xw dead), N*F2
    float* v   = A + (size_t)NN * F2;      // SAGE v = h1@wr, N*F2
    float* hw  = A;                        // GCN gemm out (u dead), N*F2
    float* h3  = A + (size_t)NN * F2;      // GCN gather out (v dead), N*F2

    // ---- CSR build ----
    hipMemsetAsync(degi, 0, sizeof(int) * NN, stream);
    k_count<<<(NE + 255) / 256, 256, 0, stream>>>(ei, degi);
    k_scan1<<<NB_SCAN, 256, 0, stream>>>(degi, rowptr, bsum);
    k_scan2<<<1, 512, 0, stream>>>(bsum, NB_SCAN);
    k_scan3<<<NB_SCAN, 256, 0, stream>>>(rowptr, cursor, bsum);
    k_scatter<<<(NE + 255) / 256, 256, 0, stream>>>(ei, cursor, csr_src);

    // ---- GAT ----
    k_xw<<<NN, F1, 0, stream>>>(x, gat_w, att_src, att_dst, xw, asr, ads);
    k_gat_gather<<<(NN + 3) / 4, 256, 0, stream>>>(rowptr, csr_src, asr, ads, xw, h1);
    hipMemsetAsync(sums, 0, sizeof(float) * 256, stream);
    k_bn_stats<<<512, F1, 0, stream>>>(h1, F1, sums);
    k_bn_apply<<<(NN * F1 + 255) / 256, 256, 0, stream>>>(h1, sums, bn1_g, bn1_b, F1, NN * F1);

    // ---- SAGE: dense dual-GEMM first, then 64-wide mean-gather (linearity) ----
    k_sage_dualgemm<<<NN / GROWS, 256, 0, stream>>>(h1, sage_wl, sage_wr, u, v);
    k_sage_gather2<<<(NN + 3) / 4, 256, 0, stream>>>(rowptr, csr_src, u, v, sage_bl, h2);
    hipMemsetAsync(sums, 0, sizeof(float) * 256, stream);
    k_bn_stats<<<512, F2, 0, stream>>>(h2, F2, sums);
    k_bn_apply<<<(NN * F2 + 255) / 256, 256, 0, stream>>>(h2, sums, bn2_g, bn2_b, F2, NN * F2);

    // ---- GCN ----
    k_dinv<<<(NN + 255) / 256, 256, 0, stream>>>(degi, dinv);
    k_gcn_gemm<<<NN / GROWS, 256, 0, stream>>>(h2, gcn_w, hw);
    k_gcn_gather<<<(NN + 3) / 4, 256, 0, stream>>>(rowptr, csr_src, hw, dinv, gcn_b, h3);
    hipMemsetAsync(sums, 0, sizeof(float) * 256, stream);
    k_bn_stats<<<512, F2, 0, stream>>>(h3, F2, sums);

    // ---- fused BN3 + ELU + pooling, then classifier ----
    hipMemsetAsync(psum, 0, sizeof(float) * NG * F2, stream);
    hipMemsetAsync(cnt, 0, sizeof(float) * NG, stream);
    k_fill_u32<<<(NG * F2 + 255) / 256, 256, 0, stream>>>(pmax, ENC_NEG_INF, NG * F2);
    k_bn3_pool<<<512, F2, 0, stream>>>(h3, sums, bn3_g, bn3_b, batch, psum, pmax, cnt);
    k_cls<<<NG, F2, 0, stream>>>(psum, pmax, cnt, w1, b1, w2, b2, out);
}

// Round 9
// 1240.873 us; speedup vs baseline: 2.8557x; 1.0394x over previous
//
#include <hip/hip_runtime.h>
#include <hip/hip_bf16.h>
#include <math.h>

#define NN 100000      // nodes
#define NE 1600000     // edges
#define NG 64          // graphs
#define F_IN 5
#define F1 128         // H*HID
#define F2 64          // HID
#define NCLS 4
#define NB_SCAN ((NN + 255) / 256)   // 391 blocks in scan level 1
#define GROWS 32                     // rows per block in register-blocked GEMMs

typedef unsigned short ushort;

// ---------- bf16 helpers (round-to-nearest-even pack) ----------
__device__ __forceinline__ ushort f2bf(float f) {
    unsigned u = __float_as_uint(f);
    u = (u + 0x7fffu + ((u >> 16) & 1u)) >> 16;
    return (ushort)u;
}
__device__ __forceinline__ float bf2f(ushort h) {
    return __uint_as_float(((unsigned)h) << 16);
}
__device__ __forceinline__ unsigned pack2bf(float a, float b) {
    return (unsigned)f2bf(a) | ((unsigned)f2bf(b) << 16);
}

// ---------- order-preserving float<->uint encoding for atomicMax ----------
__device__ __forceinline__ unsigned enc_f(float f) {
    unsigned b = __float_as_uint(f);
    return (b & 0x80000000u) ? ~b : (b | 0x80000000u);
}
__device__ __forceinline__ float dec_f(unsigned k) {
    unsigned b = (k & 0x80000000u) ? (k ^ 0x80000000u) : ~k;
    return __uint_as_float(b);
}
#define ENC_NEG_INF 0x007FFFFFu   // enc_f(-inf)

__global__ void k_fill_u32(unsigned* p, unsigned v, int n) {
    int i = blockIdx.x * blockDim.x + threadIdx.x;
    if (i < n) p[i] = v;
}

// =================== CSR build (sort edges by dst, no payload) ===================
__global__ void k_count(const int* __restrict__ ei, int* __restrict__ degi) {
    int e = blockIdx.x * blockDim.x + threadIdx.x;
    if (e < NE) atomicAdd(&degi[ei[NE + e]], 1);
}

__global__ void k_scan1(const int* __restrict__ degi, int* __restrict__ rowptr,
                        int* __restrict__ bsum) {
    __shared__ int sh[256];
    int i = blockIdx.x * 256 + threadIdx.x;
    int v = (i < NN) ? degi[i] : 0;
    sh[threadIdx.x] = v;
    __syncthreads();
    for (int off = 1; off < 256; off <<= 1) {
        int t = (threadIdx.x >= off) ? sh[threadIdx.x - off] : 0;
        __syncthreads();
        sh[threadIdx.x] += t;
        __syncthreads();
    }
    if (i < NN) rowptr[i] = sh[threadIdx.x] - v;   // exclusive, block-local
    if (threadIdx.x == 255) bsum[blockIdx.x] = sh[255];
}

__global__ void k_scan2(int* __restrict__ bsum, int nb) {
    __shared__ int sh[512];
    int v = (threadIdx.x < nb) ? bsum[threadIdx.x] : 0;
    sh[threadIdx.x] = v;
    __syncthreads();
    for (int off = 1; off < 512; off <<= 1) {
        int t = (threadIdx.x >= off) ? sh[threadIdx.x - off] : 0;
        __syncthreads();
        sh[threadIdx.x] += t;
        __syncthreads();
    }
    if (threadIdx.x < nb) bsum[threadIdx.x] = sh[threadIdx.x] - v;   // exclusive
}

__global__ void k_scan3(int* __restrict__ rowptr, int* __restrict__ cursor,
                        const int* __restrict__ bsum) {
    int i = blockIdx.x * 256 + threadIdx.x;
    if (i == 0) rowptr[NN] = NE;
    if (i >= NN) return;
    int r = rowptr[i] + bsum[blockIdx.x];
    rowptr[i] = r;
    cursor[i] = r;
}

__global__ void k_scatter(const int* __restrict__ ei, int* __restrict__ cursor,
                          int* __restrict__ csr_src) {
    int e = blockIdx.x * blockDim.x + threadIdx.x;
    if (e >= NE) return;
    int d = ei[NE + e];
    int pos = atomicAdd(&cursor[d], 1);
    csr_src[pos] = ei[e];
}

// =================== GAT ===================
// xw (bf16) = x @ gat_w ; a_src/a_dst per-node attention logits
__global__ void k_xw(const float* __restrict__ x, const float* __restrict__ gw,
                     const float* __restrict__ aw_src, const float* __restrict__ aw_dst,
                     ushort* __restrict__ xw_bf, float* __restrict__ a_src,
                     float* __restrict__ a_dst) {
    int n = blockIdx.x;
    int f = threadIdx.x;                 // 128 threads, f = h*64+c
    __shared__ float w[F_IN * F1];
    __shared__ float xs[F_IN];
    for (int i = f; i < F_IN * F1; i += F1) w[i] = gw[i];
    if (f < F_IN) xs[f] = x[n * F_IN + f];
    __syncthreads();
    float acc = 0.f;
#pragma unroll
    for (int i = 0; i < F_IN; i++) acc += xs[i] * w[i * F1 + f];
    xw_bf[n * F1 + f] = f2bf(acc);
    int h = f >> 6, lane = f & 63;
    float p = acc * aw_src[f];
    float q = acc * aw_dst[f];
#pragma unroll
    for (int off = 32; off > 0; off >>= 1) {
        p += __shfl_down(p, off);
        q += __shfl_down(q, off);
    }
    if (lane == 0) { a_src[n * 2 + h] = p; a_dst[n * 2 + h] = q; }
}

// per-node softmax over incoming edges, one THREAD per node (no redundant lanes).
// 3 passes over the node's CSR segment: max -> exp+sum -> normalize.
// alpha[j] = packed 2xbf16 normalized attention (head0, head1), CSR edge order.
__global__ void k_alpha(const int* __restrict__ rowptr, const int* __restrict__ csr_src,
                        const float* __restrict__ a_src, const float* __restrict__ a_dst,
                        unsigned* __restrict__ alpha) {
    int n = blockIdx.x * blockDim.x + threadIdx.x;
    if (n >= NN) return;
    int j0 = rowptr[n], j1 = rowptr[n + 1];
    if (j0 == j1) return;
    float ad0 = a_dst[n * 2 + 0], ad1 = a_dst[n * 2 + 1];
    float m0 = -INFINITY, m1 = -INFINITY;
    for (int j = j0; j < j1; j++) {
        int s = csr_src[j];
        float l0 = a_src[s * 2 + 0] + ad0;
        float l1 = a_src[s * 2 + 1] + ad1;
        l0 = l0 > 0.f ? l0 : 0.2f * l0;
        l1 = l1 > 0.f ? l1 : 0.2f * l1;
        m0 = fmaxf(m0, l0); m1 = fmaxf(m1, l1);
    }
    float s0 = 0.f, s1 = 0.f;
    for (int j = j0; j < j1; j++) {
        int s = csr_src[j];
        float l0 = a_src[s * 2 + 0] + ad0;
        float l1 = a_src[s * 2 + 1] + ad1;
        l0 = l0 > 0.f ? l0 : 0.2f * l0;
        l1 = l1 > 0.f ? l1 : 0.2f * l1;
        float e0 = expf(l0 - m0), e1 = expf(l1 - m1);
        s0 += e0; s1 += e1;
        alpha[j] = pack2bf(e0, e1);
    }
    float r0 = 1.0f / (s0 + 1e-16f), r1 = 1.0f / (s1 + 1e-16f);
    for (int j = j0; j < j1; j++) {
        unsigned a = alpha[j];
        float e0 = bf2f((ushort)(a & 0xffffu)) * r0;
        float e1 = bf2f((ushort)(a >> 16)) * r1;
        alpha[j] = pack2bf(e0, e1);
    }
}

// pure gather-accumulate: one wave per dst node, lane covers feats (2l, 2l+1).
// per edge: uniform idx + uniform alpha + one 4B vector load + 2 FMA.
__global__ void k_gat_gather(const int* __restrict__ rowptr, const int* __restrict__ csr_src,
                             const unsigned* __restrict__ alpha,
                             const unsigned* __restrict__ xw32, float* __restrict__ h1) {
    int n = blockIdx.x * 4 + (threadIdx.x >> 6);
    int lane = threadIdx.x & 63;
    if (n >= NN) return;
    int j0 = rowptr[n], j1 = rowptr[n + 1];
    float acc0 = 0.f, acc1 = 0.f;
    for (int j = j0; j < j1; j++) {
        int s = csr_src[j];
        unsigned aw = alpha[j];
        // lane<32 -> feats 0..63 (head0) ; lane>=32 -> feats 64..127 (head1)
        float w = (lane < 32) ? __uint_as_float(aw << 16)
                              : __uint_as_float(aw & 0xffff0000u);
        unsigned px = xw32[(size_t)s * 64 + lane];
        acc0 = fmaf(__uint_as_float(px << 16), w, acc0);
        acc1 = fmaf(__uint_as_float(px & 0xffff0000u), w, acc1);
    }
    float2 o; o.x = acc0; o.y = acc1;
    *(float2*)&h1[(size_t)n * F1 + 2 * lane] = o;
}

// =================== BatchNorm ===================
__global__ void k_bn_stats(const float* __restrict__ h, int nfeat, float* __restrict__ sums) {
    int f = threadIdx.x;                       // blockDim.x == nfeat
    int rows = (NN + gridDim.x - 1) / gridDim.x;
    int r0 = blockIdx.x * rows;
    int r1 = min(NN, r0 + rows);
    float s = 0.f, ss = 0.f;
    for (int r = r0; r < r1; r++) {
        float v = h[r * nfeat + f];
        s += v; ss += v * v;
    }
    atomicAdd(&sums[f], s);
    atomicAdd(&sums[nfeat + f], ss);
}

__global__ void k_bn_apply(float* __restrict__ h, const float* __restrict__ sums,
                           const float* __restrict__ g, const float* __restrict__ b,
                           int nfeat, int total) {
    int i = blockIdx.x * blockDim.x + threadIdx.x;
    if (i >= total) return;
    int f = i & (nfeat - 1);
    float m = sums[f] * (1.0f / NN);
    float var = sums[nfeat + f] * (1.0f / NN) - m * m;
    float v = (h[i] - m) * rsqrtf(var + 1e-5f) * g[f] + b[f];
    h[i] = v > 0.f ? v : expm1f(v);
}

// =================== SAGE ===================
// u (bf16) = h1 @ wl ; v (f32) = h1 @ wr  — register-blocked dual GEMM.
__global__ void k_sage_dualgemm(const float* __restrict__ h1,
                                const float* __restrict__ wl, const float* __restrict__ wr,
                                ushort* __restrict__ u_bf, float* __restrict__ v) {
    __shared__ float swl[F1 * F2];   // 32 KB
    __shared__ float swr[F1 * F2];   // 32 KB
    int t = threadIdx.x;
    const float4* wl4 = (const float4*)wl;
    const float4* wr4 = (const float4*)wr;
    float4* swl4 = (float4*)swl;
    float4* swr4 = (float4*)swr;
    for (int i = t; i < F1 * F2 / 4; i += 256) { swl4[i] = wl4[i]; swr4[i] = wr4[i]; }
    __syncthreads();
    int w = t >> 6, j = t & 63;
    int row0 = blockIdx.x * GROWS + w * 8;
    float accu[8] = {0.f, 0.f, 0.f, 0.f, 0.f, 0.f, 0.f, 0.f};
    float accv[8] = {0.f, 0.f, 0.f, 0.f, 0.f, 0.f, 0.f, 0.f};
    for (int k = 0; k < F1; k += 4) {
        float4 a[8];
#pragma unroll
        for (int r = 0; r < 8; r++)
            a[r] = *(const float4*)&h1[(size_t)(row0 + r) * F1 + k];
#pragma unroll
        for (int kk = 0; kk < 4; kk++) {
            float wlj = swl[(k + kk) * F2 + j];
            float wrj = swr[(k + kk) * F2 + j];
#pragma unroll
            for (int r = 0; r < 8; r++) {
                float av = (&a[r].x)[kk];
                accu[r] += av * wlj;
                accv[r] += av * wrj;
            }
        }
    }
#pragma unroll
    for (int r = 0; r < 8; r++) {
        u_bf[(size_t)(row0 + r) * F2 + j] = f2bf(accu[r]);
        v[(size_t)(row0 + r) * F2 + j] = accv[r];
    }
}

// h2[n] = mean-gather(u_bf16) + v[n] + bl   (128 B/edge)
__global__ void k_sage_gather2(const int* __restrict__ rowptr, const int* __restrict__ csr_src,
                               const ushort* __restrict__ u_bf, const float* __restrict__ v,
                               const float* __restrict__ bl, float* __restrict__ h2) {
    int n = blockIdx.x * 4 + (threadIdx.x >> 6);
    int lane = threadIdx.x & 63;
    if (n >= NN) return;
    int j0 = rowptr[n], j1 = rowptr[n + 1];
    float a = 0.f;
    for (int j = j0; j < j1; j++) {
        int s = csr_src[j];
        a += bf2f(u_bf[(size_t)s * F2 + lane]);
    }
    float inv = 1.0f / fmaxf((float)(j1 - j0), 1.0f);
    h2[(size_t)n * F2 + lane] = a * inv + v[(size_t)n * F2 + lane] + bl[lane];
}

__global__ void k_dinv(const int* __restrict__ degi, float* __restrict__ dinv) {
    int i = blockIdx.x * blockDim.x + threadIdx.x;
    if (i < NN) dinv[i] = rsqrtf((float)degi[i] + 1.0f);
}

// =================== GCN ===================
// hwd (bf16) = (h2 @ gcn_w) * dinv[row]  — pre-scaled by src norm factor.
__global__ void k_gcn_gemm(const float* __restrict__ h2, const float* __restrict__ wmat,
                           const float* __restrict__ dinv, ushort* __restrict__ hwd_bf) {
    __shared__ float sw[F2 * F2];    // 16 KB
    int t = threadIdx.x;
    const float4* w4 = (const float4*)wmat;
    float4* sw4 = (float4*)sw;
    for (int i = t; i < F2 * F2 / 4; i += 256) sw4[i] = w4[i];
    __syncthreads();
    int w = t >> 6, j = t & 63;
    int row0 = blockIdx.x * GROWS + w * 8;
    float acc[8] = {0.f, 0.f, 0.f, 0.f, 0.f, 0.f, 0.f, 0.f};
    for (int k = 0; k < F2; k += 4) {
        float4 a[8];
#pragma unroll
        for (int r = 0; r < 8; r++)
            a[r] = *(const float4*)&h2[(size_t)(row0 + r) * F2 + k];
#pragma unroll
        for (int kk = 0; kk < 4; kk++) {
            float wkj = sw[(k + kk) * F2 + j];
#pragma unroll
            for (int r = 0; r < 8; r++)
                acc[r] += (&a[r].x)[kk] * wkj;
        }
    }
#pragma unroll
    for (int r = 0; r < 8; r++)
        hwd_bf[(size_t)(row0 + r) * F2 + j] = f2bf(acc[r] * dinv[row0 + r]);
}

// h3 = dinv[n]*(sum_src hwd[s] + hwd[n]) + gb   (self-loop folded in)
__global__ void k_gcn_gather(const int* __restrict__ rowptr, const int* __restrict__ csr_src,
                             const ushort* __restrict__ hwd_bf, const float* __restrict__ dinv,
                             const float* __restrict__ gb, float* __restrict__ h3) {
    int n = blockIdx.x * 4 + (threadIdx.x >> 6);
    int lane = threadIdx.x & 63;
    if (n >= NN) return;
    int j0 = rowptr[n], j1 = rowptr[n + 1];
    float acc = 0.f;
    for (int j = j0; j < j1; j++) {
        int s = csr_src[j];
        acc += bf2f(hwd_bf[(size_t)s * F2 + lane]);
    }
    float di = dinv[n];
    acc += bf2f(hwd_bf[(size_t)n * F2 + lane]);
    h3[(size_t)n * F2 + lane] = acc * di + gb[lane];
}

// =================== fused BN3-apply + ELU + segmented pool ===================
__global__ void k_bn3_pool(const float* __restrict__ h3raw, const float* __restrict__ sums,
                           const float* __restrict__ g3, const float* __restrict__ b3,
                           const int* __restrict__ batch, float* __restrict__ psum,
                           unsigned* __restrict__ pmax, float* __restrict__ cnt) {
    int lane = threadIdx.x;   // 64 threads = one wave, lane = feature
    int rows = (NN + gridDim.x - 1) / gridDim.x;
    int r0 = blockIdx.x * rows;
    int r1 = min(NN, r0 + rows);
    if (r0 >= r1) return;
    float m = sums[lane] * (1.0f / NN);
    float var = sums[F2 + lane] * (1.0f / NN) - m * m;
    float sc = rsqrtf(var + 1e-5f) * g3[lane];
    float bb = b3[lane];
    int curg = batch[r0];
    float ls = 0.f, lm = -INFINITY;
    int run = 0;
    for (int r = r0; r < r1; r++) {
        int gg = batch[r];
        if (gg != curg) {
            atomicAdd(&psum[curg * F2 + lane], ls);
            atomicMax(&pmax[curg * F2 + lane], enc_f(lm));
            if (lane == 0) atomicAdd(&cnt[curg], (float)run);
            curg = gg; ls = 0.f; lm = -INFINITY; run = 0;
        }
        float v = (h3raw[r * F2 + lane] - m) * sc + bb;
        v = v > 0.f ? v : expm1f(v);
        ls += v; lm = fmaxf(lm, v); run++;
    }
    atomicAdd(&psum[curg * F2 + lane], ls);
    atomicMax(&pmax[curg * F2 + lane], enc_f(lm));
    if (lane == 0) atomicAdd(&cnt[curg], (float)run);
}

// =================== classifier ===================
__global__ void k_cls(const float* __restrict__ psum, const unsigned* __restrict__ pmax,
                      const float* __restrict__ cnt, const float* __restrict__ w1,
                      const float* __restrict__ b1, const float* __restrict__ w2,
                      const float* __restrict__ b2, float* __restrict__ out) {
    int g = blockIdx.x;
    int j = threadIdx.x;  // 64 threads
    __shared__ float z[2 * F2];
    __shared__ float hid[F2];
    float c = fmaxf(cnt[g], 1.0f);
    z[j] = psum[g * F2 + j] / c;
    float mv = dec_f(pmax[g * F2 + j]);
    z[F2 + j] = isfinite(mv) ? mv : 0.f;
    __syncthreads();
    float acc = b1[j];
#pragma unroll 8
    for (int k = 0; k < 2 * F2; k++) acc += z[k] * w1[k * F2 + j];
    hid[j] = fmaxf(acc, 0.f);
    __syncthreads();
    if (j < NCLS) {
        float o = b2[j];
#pragma unroll 8
        for (int k = 0; k < F2; k++) o += hid[k] * w2[k * NCLS + j];
        out[g * NCLS + j] = o;
    }
}

extern "C" void kernel_launch(void* const* d_in, const int* in_sizes, int n_in,
                              void* d_out, int out_size, void* d_ws, size_t ws_size,
                              hipStream_t stream) {
    const float* x       = (const float*)d_in[0];
    const int*   ei      = (const int*)d_in[1];
    const int*   batch   = (const int*)d_in[2];
    const float* gat_w   = (const float*)d_in[3];
    const float* att_src = (const float*)d_in[4];
    const float* att_dst = (const float*)d_in[5];
    // d_in[6] gat_b: cancels inside BN1 (constant shift removed by mean subtraction)
    const float* bn1_g   = (const float*)d_in[7];
    const float* bn1_b   = (const float*)d_in[8];
    const float* sage_wl = (const float*)d_in[9];
    const float* sage_bl = (const float*)d_in[10];
    const float* sage_wr = (const float*)d_in[11];
    const float* bn2_g   = (const float*)d_in[12];
    const float* bn2_b   = (const float*)d_in[13];
    const float* gcn_w   = (const float*)d_in[14];
    const float* gcn_b   = (const float*)d_in[15];
    const float* bn3_g   = (const float*)d_in[16];
    const float* bn3_b   = (const float*)d_in[17];
    const float* w1      = (const float*)d_in[18];
    const float* b1      = (const float*)d_in[19];
    const float* w2      = (const float*)d_in[20];
    const float* b2      = (const float*)d_in[21];
    float* out = (float*)d_out;

    float* ws = (float*)d_ws;
    // workspace layout (4-byte units)
    size_t o_A    = 0;                        // NN*F1 floats region, aliased (see below)
    size_t o_h1   = o_A   + (size_t)NN * F1;  // NN*F1 f32: GAT output (post-BN1)
    size_t o_h2   = o_h1  + (size_t)NN * F1;  // NN*F2 f32
    size_t o_csr  = o_h2  + (size_t)NN * F2;  // E ints (csr_src)
    size_t o_rp   = o_csr + (size_t)NE;       // N+1 ints (rowptr)
    size_t o_cur  = o_rp  + (size_t)(NN + 1); // N ints (cursor)
    size_t o_deg  = o_cur + (size_t)NN;       // N ints (degi)
    size_t o_bs   = o_deg + (size_t)NN;       // 512 ints (block sums)
    size_t o_asrc = o_bs  + 512;              // N*2
    size_t o_adst = o_asrc + (size_t)NN * 2;  // N*2
    size_t o_dinv = o_adst + (size_t)NN * 2;  // N
    size_t o_sums = o_dinv + (size_t)NN;      // 256
    size_t o_psum = o_sums + 256;             // G*F2
    size_t o_pmax = o_psum + (size_t)NG * F2; // G*F2
    size_t o_cnt  = o_pmax + (size_t)NG * F2; // G
    size_t o_alp  = o_cnt + (size_t)NG;       // E uints (packed 2xbf16 alpha)

    float* A    = ws + o_A;
    float* h1   = ws + o_h1;
    float* h2   = ws + o_h2;
    int* csr_src = (int*)(ws + o_csr);
    int* rowptr  = (int*)(ws + o_rp);
    int* cursor  = (int*)(ws + o_cur);
    int* degi    = (int*)(ws + o_deg);
    int* bsum    = (int*)(ws + o_bs);
    float* asr  = ws + o_asrc;
    float* ads  = ws + o_adst;
    float* dinv = ws + o_dinv;
    float* sums = ws + o_sums;
    float* psum = ws + o_psum;
    unsigned* pmax = (unsigned*)(ws + o_pmax);
    float* cnt  = ws + o_cnt;
    unsigned* alpha = (unsigned*)(ws + o_alp);

    // region-A role aliases (lifetimes disjoint):
    ushort* xw_bf  = (ushort*)A;                        // GAT: NN*F1 bf16 (25.6 MB)
    ushort* u_bf   = (ushort*)A;                        // SAGE: NN*F2 bf16 (xw dead)
    float*  vmat   = A + (size_t)NN * F2 / 2;           // SAGE: NN*F2 f32
    ushort* hwd_bf = (ushort*)A;                        // GCN: NN*F2 bf16 (u dead)
    float*  h3     = A + (size_t)NN * F2 / 2;           // GCN out: NN*F2 f32 (v dead)

    // ---- CSR build ----
    hipMemsetAsync(degi, 0, sizeof(int) * NN, stream);
    k_count<<<(NE + 255) / 256, 256, 0, stream>>>(ei, degi);
    k_scan1<<<NB_SCAN, 256, 0, stream>>>(degi, rowptr, bsum);
    k_scan2<<<1, 512, 0, stream>>>(bsum, NB_SCAN);
    k_scan3<<<NB_SCAN, 256, 0, stream>>>(rowptr, cursor, bsum);
    k_scatter<<<(NE + 255) / 256, 256, 0, stream>>>(ei, cursor, csr_src);

    // ---- GAT ----
    k_xw<<<NN, F1, 0, stream>>>(x, gat_w, att_src, att_dst, xw_bf, asr, ads);
    k_alpha<<<(NN + 255) / 256, 256, 0, stream>>>(rowptr, csr_src, asr, ads, alpha);
    k_gat_gather<<<(NN + 3) / 4, 256, 0, stream>>>(rowptr, csr_src, alpha,
                                                   (const unsigned*)xw_bf, h1);
    hipMemsetAsync(sums, 0, sizeof(float) * 256, stream);
    k_bn_stats<<<512, F1, 0, stream>>>(h1, F1, sums);
    k_bn_apply<<<(NN * F1 + 255) / 256, 256, 0, stream>>>(h1, sums, bn1_g, bn1_b, F1, NN * F1);

    // ---- SAGE: dense dual-GEMM first, then bf16 mean-gather (linearity) ----
    k_sage_dualgemm<<<NN / GROWS, 256, 0, stream>>>(h1, sage_wl, sage_wr, u_bf, vmat);
    k_sage_gather2<<<(NN + 3) / 4, 256, 0, stream>>>(rowptr, csr_src, u_bf, vmat, sage_bl, h2);
    hipMemsetAsync(sums, 0, sizeof(float) * 256, stream);
    k_bn_stats<<<512, F2, 0, stream>>>(h2, F2, sums);
    k_bn_apply<<<(NN * F2 + 255) / 256, 256, 0, stream>>>(h2, sums, bn2_g, bn2_b, F2, NN * F2);

    // ---- GCN ----
    k_dinv<<<(NN + 255) / 256, 256, 0, stream>>>(degi, dinv);
    k_gcn_gemm<<<NN / GROWS, 256, 0, stream>>>(h2, gcn_w, dinv, hwd_bf);
    k_gcn_gather<<<(NN + 3) / 4, 256, 0, stream>>>(rowptr, csr_src, hwd_bf, dinv, gcn_b, h3);
    hipMemsetAsync(sums, 0, sizeof(float) * 256, stream);
    k_bn_stats<<<512, F2, 0, stream>>>(h3, F2, sums);

    // ---- fused BN3 + ELU + pooling, then classifier ----
    hipMemsetAsync(psum, 0, sizeof(float) * NG * F2, stream);
    hipMemsetAsync(cnt, 0, sizeof(float) * NG, stream);
    k_fill_u32<<<(NG * F2 + 255) / 256, 256, 0, stream>>>(pmax, ENC_NEG_INF, NG * F2);
    k_bn3_pool<<<512, F2, 0, stream>>>(h3, sums, bn3_g, bn3_b, batch, psum, pmax, cnt);
    k_cls<<<NG, F2, 0, stream>>>(psum, pmax, cnt, w1, b1, w2, b2, out);
}

// Round 10
// 953.469 us; speedup vs baseline: 3.7165x; 1.3014x over previous
//
#include <hip/hip_runtime.h>
#include <hip/hip_bf16.h>
#include <math.h>

#define NN 100000      // nodes
#define NE 1600000     // edges
#define NG 64          // graphs
#define F_IN 5
#define F1 128         // H*HID
#define F2 64          // HID
#define NCLS 4
#define NB_SCAN ((NN + 255) / 256)   // 391 blocks in scan level 1
#define GROWS 32                     // rows per block in register-blocked GEMMs

typedef unsigned short ushort;

// ---------- bf16 helpers (round-to-nearest-even pack) ----------
__device__ __forceinline__ ushort f2bf(float f) {
    unsigned u = __float_as_uint(f);
    u = (u + 0x7fffu + ((u >> 16) & 1u)) >> 16;
    return (ushort)u;
}
__device__ __forceinline__ float bf2f(ushort h) {
    return __uint_as_float(((unsigned)h) << 16);
}
__device__ __forceinline__ unsigned pack2bf(float a, float b) {
    return (unsigned)f2bf(a) | ((unsigned)f2bf(b) << 16);
}
__device__ __forceinline__ float lo_bf(unsigned p) { return __uint_as_float(p << 16); }
__device__ __forceinline__ float hi_bf(unsigned p) { return __uint_as_float(p & 0xffff0000u); }

// ---------- order-preserving float<->uint encoding for atomicMax ----------
__device__ __forceinline__ unsigned enc_f(float f) {
    unsigned b = __float_as_uint(f);
    return (b & 0x80000000u) ? ~b : (b | 0x80000000u);
}
__device__ __forceinline__ float dec_f(unsigned k) {
    unsigned b = (k & 0x80000000u) ? (k ^ 0x80000000u) : ~k;
    return __uint_as_float(b);
}
#define ENC_NEG_INF 0x007FFFFFu   // enc_f(-inf)

__global__ void k_fill_u32(unsigned* p, unsigned v, int n) {
    int i = blockIdx.x * blockDim.x + threadIdx.x;
    if (i < n) p[i] = v;
}

// =================== CSR build (sort edges by dst, no payload) ===================
__global__ void k_count(const int* __restrict__ ei, int* __restrict__ degi) {
    int e = blockIdx.x * blockDim.x + threadIdx.x;
    if (e < NE) atomicAdd(&degi[ei[NE + e]], 1);
}

__global__ void k_scan1(const int* __restrict__ degi, int* __restrict__ rowptr,
                        int* __restrict__ bsum) {
    __shared__ int sh[256];
    int i = blockIdx.x * 256 + threadIdx.x;
    int v = (i < NN) ? degi[i] : 0;
    sh[threadIdx.x] = v;
    __syncthreads();
    for (int off = 1; off < 256; off <<= 1) {
        int t = (threadIdx.x >= off) ? sh[threadIdx.x - off] : 0;
        __syncthreads();
        sh[threadIdx.x] += t;
        __syncthreads();
    }
    if (i < NN) rowptr[i] = sh[threadIdx.x] - v;   // exclusive, block-local
    if (threadIdx.x == 255) bsum[blockIdx.x] = sh[255];
}

__global__ void k_scan2(int* __restrict__ bsum, int nb) {
    __shared__ int sh[512];
    int v = (threadIdx.x < nb) ? bsum[threadIdx.x] : 0;
    sh[threadIdx.x] = v;
    __syncthreads();
    for (int off = 1; off < 512; off <<= 1) {
        int t = (threadIdx.x >= off) ? sh[threadIdx.x - off] : 0;
        __syncthreads();
        sh[threadIdx.x] += t;
        __syncthreads();
    }
    if (threadIdx.x < nb) bsum[threadIdx.x] = sh[threadIdx.x] - v;   // exclusive
}

__global__ void k_scan3(int* __restrict__ rowptr, int* __restrict__ cursor,
                        const int* __restrict__ bsum) {
    int i = blockIdx.x * 256 + threadIdx.x;
    if (i == 0) rowptr[NN] = NE;
    if (i >= NN) return;
    int r = rowptr[i] + bsum[blockIdx.x];
    rowptr[i] = r;
    cursor[i] = r;
}

__global__ void k_scatter(const int* __restrict__ ei, int* __restrict__ cursor,
                          int* __restrict__ csr_src) {
    int e = blockIdx.x * blockDim.x + threadIdx.x;
    if (e >= NE) return;
    int d = ei[NE + e];
    int pos = atomicAdd(&cursor[d], 1);
    csr_src[pos] = ei[e];
}

// =================== GAT ===================
// xw (bf16) = x @ gat_w ; a_src/a_dst per-node attention logits
__global__ void k_xw(const float* __restrict__ x, const float* __restrict__ gw,
                     const float* __restrict__ aw_src, const float* __restrict__ aw_dst,
                     ushort* __restrict__ xw_bf, float* __restrict__ a_src,
                     float* __restrict__ a_dst) {
    int n = blockIdx.x;
    int f = threadIdx.x;                 // 128 threads, f = h*64+c
    __shared__ float w[F_IN * F1];
    __shared__ float xs[F_IN];
    for (int i = f; i < F_IN * F1; i += F1) w[i] = gw[i];
    if (f < F_IN) xs[f] = x[n * F_IN + f];
    __syncthreads();
    float acc = 0.f;
#pragma unroll
    for (int i = 0; i < F_IN; i++) acc += xs[i] * w[i * F1 + f];
    xw_bf[n * F1 + f] = f2bf(acc);
    int h = f >> 6, lane = f & 63;
    float p = acc * aw_src[f];
    float q = acc * aw_dst[f];
#pragma unroll
    for (int off = 32; off > 0; off >>= 1) {
        p += __shfl_down(p, off);
        q += __shfl_down(q, off);
    }
    if (lane == 0) { a_src[n * 2 + h] = p; a_dst[n * 2 + h] = q; }
}

// per-node softmax over incoming edges, ONE WAVE per node, lane-per-edge.
// fast path deg<=64: single parallel pass + shfl reductions, normalized store.
__global__ void k_alpha(const int* __restrict__ rowptr, const int* __restrict__ csr_src,
                        const float* __restrict__ a_src, const float* __restrict__ a_dst,
                        unsigned* __restrict__ alpha) {
    int n = blockIdx.x * 4 + (threadIdx.x >> 6);
    int lane = threadIdx.x & 63;
    if (n >= NN) return;
    int j0 = rowptr[n], j1 = rowptr[n + 1];
    int deg = j1 - j0;
    if (deg <= 0) return;
    float ad0 = a_dst[n * 2 + 0], ad1 = a_dst[n * 2 + 1];
    if (deg <= 64) {
        int j = j0 + lane;
        float l0 = -INFINITY, l1 = -INFINITY;
        if (lane < deg) {
            int s = csr_src[j];
            l0 = a_src[s * 2 + 0] + ad0;
            l1 = a_src[s * 2 + 1] + ad1;
            l0 = l0 > 0.f ? l0 : 0.2f * l0;
            l1 = l1 > 0.f ? l1 : 0.2f * l1;
        }
        float m0 = l0, m1 = l1;
#pragma unroll
        for (int off = 32; off > 0; off >>= 1) {
            m0 = fmaxf(m0, __shfl_xor(m0, off));
            m1 = fmaxf(m1, __shfl_xor(m1, off));
        }
        float e0 = 0.f, e1 = 0.f;
        if (lane < deg) { e0 = expf(l0 - m0); e1 = expf(l1 - m1); }
        float s0 = e0, s1 = e1;
#pragma unroll
        for (int off = 32; off > 0; off >>= 1) {
            s0 += __shfl_xor(s0, off);
            s1 += __shfl_xor(s1, off);
        }
        if (lane < deg)
            alpha[j] = pack2bf(e0 / (s0 + 1e-16f), e1 / (s1 + 1e-16f));
    } else {
        // chunked 3-pass fallback (deg > 64: statistically rare)
        float m0 = -INFINITY, m1 = -INFINITY;
        for (int base = j0; base < j1; base += 64) {
            int j = base + lane;
            float l0 = -INFINITY, l1 = -INFINITY;
            if (j < j1) {
                int s = csr_src[j];
                l0 = a_src[s * 2 + 0] + ad0;
                l1 = a_src[s * 2 + 1] + ad1;
                l0 = l0 > 0.f ? l0 : 0.2f * l0;
                l1 = l1 > 0.f ? l1 : 0.2f * l1;
            }
            m0 = fmaxf(m0, l0); m1 = fmaxf(m1, l1);
        }
#pragma unroll
        for (int off = 32; off > 0; off >>= 1) {
            m0 = fmaxf(m0, __shfl_xor(m0, off));
            m1 = fmaxf(m1, __shfl_xor(m1, off));
        }
        float s0 = 0.f, s1 = 0.f;
        for (int base = j0; base < j1; base += 64) {
            int j = base + lane;
            float e0 = 0.f, e1 = 0.f;
            if (j < j1) {
                int s = csr_src[j];
                float l0 = a_src[s * 2 + 0] + ad0;
                float l1 = a_src[s * 2 + 1] + ad1;
                l0 = l0 > 0.f ? l0 : 0.2f * l0;
                l1 = l1 > 0.f ? l1 : 0.2f * l1;
                e0 = expf(l0 - m0); e1 = expf(l1 - m1);
                alpha[j] = pack2bf(e0, e1);
            }
            s0 += e0; s1 += e1;
        }
#pragma unroll
        for (int off = 32; off > 0; off >>= 1) {
            s0 += __shfl_xor(s0, off);
            s1 += __shfl_xor(s1, off);
        }
        float r0 = 1.0f / (s0 + 1e-16f), r1 = 1.0f / (s1 + 1e-16f);
        for (int base = j0; base < j1; base += 64) {
            int j = base + lane;
            if (j < j1) {
                unsigned a = alpha[j];
                alpha[j] = pack2bf(lo_bf(a) * r0, hi_bf(a) * r1);
            }
        }
    }
}

// gather-accumulate with lane-preloaded indices + 4-deep row-load pipeline.
// wave per dst node; lane covers feats (2l, 2l+1) of the bf16 xw row.
__global__ void k_gat_gather(const int* __restrict__ rowptr, const int* __restrict__ csr_src,
                             const unsigned* __restrict__ alpha,
                             const unsigned* __restrict__ xw32, float* __restrict__ h1) {
    int n = blockIdx.x * 4 + (threadIdx.x >> 6);
    int lane = threadIdx.x & 63;
    if (n >= NN) return;
    int j0 = rowptr[n], j1 = rowptr[n + 1];
    float acc0 = 0.f, acc1 = 0.f;
    bool lo = (lane < 32);
    for (int base = j0; base < j1; base += 64) {
        int cnt = min(64, j1 - base);
        int myj = base + lane;
        int sl = 0; unsigned al = 0;
        if (myj < j1) { sl = csr_src[myj]; al = alpha[myj]; }
        int e = 0;
        for (; e + 4 <= cnt; e += 4) {
            int s0 = __shfl(sl, e + 0), s1 = __shfl(sl, e + 1),
                s2 = __shfl(sl, e + 2), s3 = __shfl(sl, e + 3);
            unsigned b0 = __shfl(al, e + 0), b1 = __shfl(al, e + 1),
                     b2 = __shfl(al, e + 2), b3 = __shfl(al, e + 3);
            unsigned p0 = xw32[(size_t)s0 * 64 + lane];
            unsigned p1 = xw32[(size_t)s1 * 64 + lane];
            unsigned p2 = xw32[(size_t)s2 * 64 + lane];
            unsigned p3 = xw32[(size_t)s3 * 64 + lane];
            float w0 = lo ? lo_bf(b0) : hi_bf(b0);
            float w1 = lo ? lo_bf(b1) : hi_bf(b1);
            float w2 = lo ? lo_bf(b2) : hi_bf(b2);
            float w3 = lo ? lo_bf(b3) : hi_bf(b3);
            acc0 = fmaf(lo_bf(p0), w0, acc0); acc1 = fmaf(hi_bf(p0), w0, acc1);
            acc0 = fmaf(lo_bf(p1), w1, acc0); acc1 = fmaf(hi_bf(p1), w1, acc1);
            acc0 = fmaf(lo_bf(p2), w2, acc0); acc1 = fmaf(hi_bf(p2), w2, acc1);
            acc0 = fmaf(lo_bf(p3), w3, acc0); acc1 = fmaf(hi_bf(p3), w3, acc1);
        }
        for (; e < cnt; e++) {
            int s = __shfl(sl, e); unsigned b = __shfl(al, e);
            unsigned p = xw32[(size_t)s * 64 + lane];
            float w = lo ? lo_bf(b) : hi_bf(b);
            acc0 = fmaf(lo_bf(p), w, acc0);
            acc1 = fmaf(hi_bf(p), w, acc1);
        }
    }
    float2 o; o.x = acc0; o.y = acc1;
    *(float2*)&h1[(size_t)n * F1 + 2 * lane] = o;
}

// =================== BatchNorm ===================
__global__ void k_bn_stats(const float* __restrict__ h, int nfeat, float* __restrict__ sums) {
    int f = threadIdx.x;                       // blockDim.x == nfeat
    int rows = (NN + gridDim.x - 1) / gridDim.x;
    int r0 = blockIdx.x * rows;
    int r1 = min(NN, r0 + rows);
    float s = 0.f, ss = 0.f;
    for (int r = r0; r < r1; r++) {
        float v = h[r * nfeat + f];
        s += v; ss += v * v;
    }
    atomicAdd(&sums[f], s);
    atomicAdd(&sums[nfeat + f], ss);
}

__global__ void k_bn_apply(float* __restrict__ h, const float* __restrict__ sums,
                           const float* __restrict__ g, const float* __restrict__ b,
                           int nfeat, int total) {
    int i = blockIdx.x * blockDim.x + threadIdx.x;
    if (i >= total) return;
    int f = i & (nfeat - 1);
    float m = sums[f] * (1.0f / NN);
    float var = sums[nfeat + f] * (1.0f / NN) - m * m;
    float v = (h[i] - m) * rsqrtf(var + 1e-5f) * g[f] + b[f];
    h[i] = v > 0.f ? v : expm1f(v);
}

// =================== SAGE ===================
// u (bf16) = h1 @ wl ; v (f32) = h1 @ wr  — register-blocked dual GEMM.
__global__ void k_sage_dualgemm(const float* __restrict__ h1,
                                const float* __restrict__ wl, const float* __restrict__ wr,
                                ushort* __restrict__ u_bf, float* __restrict__ v) {
    __shared__ float swl[F1 * F2];   // 32 KB
    __shared__ float swr[F1 * F2];   // 32 KB
    int t = threadIdx.x;
    const float4* wl4 = (const float4*)wl;
    const float4* wr4 = (const float4*)wr;
    float4* swl4 = (float4*)swl;
    float4* swr4 = (float4*)swr;
    for (int i = t; i < F1 * F2 / 4; i += 256) { swl4[i] = wl4[i]; swr4[i] = wr4[i]; }
    __syncthreads();
    int w = t >> 6, j = t & 63;
    int row0 = blockIdx.x * GROWS + w * 8;
    float accu[8] = {0.f, 0.f, 0.f, 0.f, 0.f, 0.f, 0.f, 0.f};
    float accv[8] = {0.f, 0.f, 0.f, 0.f, 0.f, 0.f, 0.f, 0.f};
    for (int k = 0; k < F1; k += 4) {
        float4 a[8];
#pragma unroll
        for (int r = 0; r < 8; r++)
            a[r] = *(const float4*)&h1[(size_t)(row0 + r) * F1 + k];
#pragma unroll
        for (int kk = 0; kk < 4; kk++) {
            float wlj = swl[(k + kk) * F2 + j];
            float wrj = swr[(k + kk) * F2 + j];
#pragma unroll
            for (int r = 0; r < 8; r++) {
                float av = (&a[r].x)[kk];
                accu[r] += av * wlj;
                accv[r] += av * wrj;
            }
        }
    }
#pragma unroll
    for (int r = 0; r < 8; r++) {
        u_bf[(size_t)(row0 + r) * F2 + j] = f2bf(accu[r]);
        v[(size_t)(row0 + r) * F2 + j] = accv[r];
    }
}

// h2[n] = mean-gather(u_bf16) + v[n] + bl   (preloaded idx + 4-deep pipeline)
__global__ void k_sage_gather2(const int* __restrict__ rowptr, const int* __restrict__ csr_src,
                               const ushort* __restrict__ u_bf, const float* __restrict__ v,
                               const float* __restrict__ bl, float* __restrict__ h2) {
    int n = blockIdx.x * 4 + (threadIdx.x >> 6);
    int lane = threadIdx.x & 63;
    if (n >= NN) return;
    int j0 = rowptr[n], j1 = rowptr[n + 1];
    float a = 0.f;
    for (int base = j0; base < j1; base += 64) {
        int cnt = min(64, j1 - base);
        int myj = base + lane;
        int sl = (myj < j1) ? csr_src[myj] : 0;
        int e = 0;
        for (; e + 4 <= cnt; e += 4) {
            int s0 = __shfl(sl, e + 0), s1 = __shfl(sl, e + 1),
                s2 = __shfl(sl, e + 2), s3 = __shfl(sl, e + 3);
            float t0 = bf2f(u_bf[(size_t)s0 * F2 + lane]);
            float t1 = bf2f(u_bf[(size_t)s1 * F2 + lane]);
            float t2 = bf2f(u_bf[(size_t)s2 * F2 + lane]);
            float t3 = bf2f(u_bf[(size_t)s3 * F2 + lane]);
            a += (t0 + t1) + (t2 + t3);
        }
        for (; e < cnt; e++) {
            int s = __shfl(sl, e);
            a += bf2f(u_bf[(size_t)s * F2 + lane]);
        }
    }
    float inv = 1.0f / fmaxf((float)(j1 - j0), 1.0f);
    h2[(size_t)n * F2 + lane] = a * inv + v[(size_t)n * F2 + lane] + bl[lane];
}

__global__ void k_dinv(const int* __restrict__ degi, float* __restrict__ dinv) {
    int i = blockIdx.x * blockDim.x + threadIdx.x;
    if (i < NN) dinv[i] = rsqrtf((float)degi[i] + 1.0f);
}

// =================== GCN ===================
// hwd (bf16) = (h2 @ gcn_w) * dinv[row]  — pre-scaled by src norm factor.
__global__ void k_gcn_gemm(const float* __restrict__ h2, const float* __restrict__ wmat,
                           const float* __restrict__ dinv, ushort* __restrict__ hwd_bf) {
    __shared__ float sw[F2 * F2];    // 16 KB
    int t = threadIdx.x;
    const float4* w4 = (const float4*)wmat;
    float4* sw4 = (float4*)sw;
    for (int i = t; i < F2 * F2 / 4; i += 256) sw4[i] = w4[i];
    __syncthreads();
    int w = t >> 6, j = t & 63;
    int row0 = blockIdx.x * GROWS + w * 8;
    float acc[8] = {0.f, 0.f, 0.f, 0.f, 0.f, 0.f, 0.f, 0.f};
    for (int k = 0; k < F2; k += 4) {
        float4 a[8];
#pragma unroll
        for (int r = 0; r < 8; r++)
            a[r] = *(const float4*)&h2[(size_t)(row0 + r) * F2 + k];
#pragma unroll
        for (int kk = 0; kk < 4; kk++) {
            float wkj = sw[(k + kk) * F2 + j];
#pragma unroll
            for (int r = 0; r < 8; r++)
                acc[r] += (&a[r].x)[kk] * wkj;
        }
    }
#pragma unroll
    for (int r = 0; r < 8; r++)
        hwd_bf[(size_t)(row0 + r) * F2 + j] = f2bf(acc[r] * dinv[row0 + r]);
}

// h3 = dinv[n]*(sum_src hwd[s] + hwd[n]) + gb   (preloaded idx + 4-deep pipeline)
__global__ void k_gcn_gather(const int* __restrict__ rowptr, const int* __restrict__ csr_src,
                             const ushort* __restrict__ hwd_bf, const float* __restrict__ dinv,
                             const float* __restrict__ gb, float* __restrict__ h3) {
    int n = blockIdx.x * 4 + (threadIdx.x >> 6);
    int lane = threadIdx.x & 63;
    if (n >= NN) return;
    int j0 = rowptr[n], j1 = rowptr[n + 1];
    float acc = 0.f;
    for (int base = j0; base < j1; base += 64) {
        int cnt = min(64, j1 - base);
        int myj = base + lane;
        int sl = (myj < j1) ? csr_src[myj] : 0;
        int e = 0;
        for (; e + 4 <= cnt; e += 4) {
            int s0 = __shfl(sl, e + 0), s1 = __shfl(sl, e + 1),
                s2 = __shfl(sl, e + 2), s3 = __shfl(sl, e + 3);
            float t0 = bf2f(hwd_bf[(size_t)s0 * F2 + lane]);
            float t1 = bf2f(hwd_bf[(size_t)s1 * F2 + lane]);
            float t2 = bf2f(hwd_bf[(size_t)s2 * F2 + lane]);
            float t3 = bf2f(hwd_bf[(size_t)s3 * F2 + lane]);
            acc += (t0 + t1) + (t2 + t3);
        }
        for (; e < cnt; e++) {
            int s = __shfl(sl, e);
            acc += bf2f(hwd_bf[(size_t)s * F2 + lane]);
        }
    }
    float di = dinv[n];
    acc += bf2f(hwd_bf[(size_t)n * F2 + lane]);
    h3[(size_t)n * F2 + lane] = acc * di + gb[lane];
}

// =================== fused BN3-apply + ELU + segmented pool ===================
__global__ void k_bn3_pool(const float* __restrict__ h3raw, const float* __restrict__ sums,
                           const float* __restrict__ g3, const float* __restrict__ b3,
                           const int* __restrict__ batch, float* __restrict__ psum,
                           unsigned* __restrict__ pmax, float* __restrict__ cnt) {
    int lane = threadIdx.x;   // 64 threads = one wave, lane = feature
    int rows = (NN + gridDim.x - 1) / gridDim.x;
    int r0 = blockIdx.x * rows;
    int r1 = min(NN, r0 + rows);
    if (r0 >= r1) return;
    float m = sums[lane] * (1.0f / NN);
    float var = sums[F2 + lane] * (1.0f / NN) - m * m;
    float sc = rsqrtf(var + 1e-5f) * g3[lane];
    float bb = b3[lane];
    int curg = batch[r0];
    float ls = 0.f, lm = -INFINITY;
    int run = 0;
    for (int r = r0; r < r1; r++) {
        int gg = batch[r];
        if (gg != curg) {
            atomicAdd(&psum[curg * F2 + lane], ls);
            atomicMax(&pmax[curg * F2 + lane], enc_f(lm));
            if (lane == 0) atomicAdd(&cnt[curg], (float)run);
            curg = gg; ls = 0.f; lm = -INFINITY; run = 0;
        }
        float v = (h3raw[r * F2 + lane] - m) * sc + bb;
        v = v > 0.f ? v : expm1f(v);
        ls += v; lm = fmaxf(lm, v); run++;
    }
    atomicAdd(&psum[curg * F2 + lane], ls);
    atomicMax(&pmax[curg * F2 + lane], enc_f(lm));
    if (lane == 0) atomicAdd(&cnt[curg], (float)run);
}

// =================== classifier ===================
__global__ void k_cls(const float* __restrict__ psum, const unsigned* __restrict__ pmax,
                      const float* __restrict__ cnt, const float* __restrict__ w1,
                      const float* __restrict__ b1, const float* __restrict__ w2,
                      const float* __restrict__ b2, float* __restrict__ out) {
    int g = blockIdx.x;
    int j = threadIdx.x;  // 64 threads
    __shared__ float z[2 * F2];
    __shared__ float hid[F2];
    float c = fmaxf(cnt[g], 1.0f);
    z[j] = psum[g * F2 + j] / c;
    float mv = dec_f(pmax[g * F2 + j]);
    z[F2 + j] = isfinite(mv) ? mv : 0.f;
    __syncthreads();
    float acc = b1[j];
#pragma unroll 8
    for (int k = 0; k < 2 * F2; k++) acc += z[k] * w1[k * F2 + j];
    hid[j] = fmaxf(acc, 0.f);
    __syncthreads();
    if (j < NCLS) {
        float o = b2[j];
#pragma unroll 8
        for (int k = 0; k < F2; k++) o += hid[k] * w2[k * NCLS + j];
        out[g * NCLS + j] = o;
    }
}

extern "C" void kernel_launch(void* const* d_in, const int* in_sizes, int n_in,
                              void* d_out, int out_size, void* d_ws, size_t ws_size,
                              hipStream_t stream) {
    const float* x       = (const float*)d_in[0];
    const int*   ei      = (const int*)d_in[1];
    const int*   batch   = (const int*)d_in[2];
    const float* gat_w   = (const float*)d_in[3];
    const float* att_src = (const float*)d_in[4];
    const float* att_dst = (const float*)d_in[5];
    // d_in[6] gat_b: cancels inside BN1 (constant shift removed by mean subtraction)
    const float* bn1_g   = (const float*)d_in[7];
    const float* bn1_b   = (const float*)d_in[8];
    const float* sage_wl = (const float*)d_in[9];
    const float* sage_bl = (const float*)d_in[10];
    const float* sage_wr = (const float*)d_in[11];
    const float* bn2_g   = (const float*)d_in[12];
    const float* bn2_b   = (const float*)d_in[13];
    const float* gcn_w   = (const float*)d_in[14];
    const float* gcn_b   = (const float*)d_in[15];
    const float* bn3_g   = (const float*)d_in[16];
    const float* bn3_b   = (const float*)d_in[17];
    const float* w1      = (const float*)d_in[18];
    const float* b1      = (const float*)d_in[19];
    const float* w2      = (const float*)d_in[20];
    const float* b2      = (const float*)d_in[21];
    float* out = (float*)d_out;

    float* ws = (float*)d_ws;
    // workspace layout (4-byte units)
    size_t o_A    = 0;                        // NN*F1 floats region, aliased (see below)
    size_t o_h1   = o_A   + (size_t)NN * F1;  // NN*F1 f32: GAT output (post-BN1)
    size_t o_h2   = o_h1  + (size_t)NN * F1;  // NN*F2 f32
    size_t o_csr  = o_h2  + (size_t)NN * F2;  // E ints (csr_src)
    size_t o_rp   = o_csr + (size_t)NE;       // N+1 ints (rowptr)
    size_t o_cur  = o_rp  + (size_t)(NN + 1); // N ints (cursor)
    size_t o_deg  = o_cur + (size_t)NN;       // N ints (degi)
    size_t o_bs   = o_deg + (size_t)NN;       // 512 ints (block sums)
    size_t o_asrc = o_bs  + 512;              // N*2
    size_t o_adst = o_asrc + (size_t)NN * 2;  // N*2
    size_t o_dinv = o_adst + (size_t)NN * 2;  // N
    size_t o_sums = o_dinv + (size_t)NN;      // 256
    size_t o_psum = o_sums + 256;             // G*F2
    size_t o_pmax = o_psum + (size_t)NG * F2; // G*F2
    size_t o_cnt  = o_pmax + (size_t)NG * F2; // G
    size_t o_alp  = o_cnt + (size_t)NG;       // E uints (packed 2xbf16 alpha)

    float* A    = ws + o_A;
    float* h1   = ws + o_h1;
    float* h2   = ws + o_h2;
    int* csr_src = (int*)(ws + o_csr);
    int* rowptr  = (int*)(ws + o_rp);
    int* cursor  = (int*)(ws + o_cur);
    int* degi    = (int*)(ws + o_deg);
    int* bsum    = (int*)(ws + o_bs);
    float* asr  = ws + o_asrc;
    float* ads  = ws + o_adst;
    float* dinv = ws + o_dinv;
    float* sums = ws + o_sums;
    float* psum = ws + o_psum;
    unsigned* pmax = (unsigned*)(ws + o_pmax);
    float* cnt  = ws + o_cnt;
    unsigned* alpha = (unsigned*)(ws + o_alp);

    // region-A role aliases (lifetimes disjoint):
    ushort* xw_bf  = (ushort*)A;                        // GAT: NN*F1 bf16 (25.6 MB)
    ushort* u_bf   = (ushort*)A;                        // SAGE: NN*F2 bf16 (xw dead)
    float*  vmat   = A + (size_t)NN * F2 / 2;           // SAGE: NN*F2 f32
    ushort* hwd_bf = (ushort*)A;                        // GCN: NN*F2 bf16 (u dead)
    float*  h3     = A + (size_t)NN * F2 / 2;           // GCN out: NN*F2 f32 (v dead)

    // ---- CSR build ----
    hipMemsetAsync(degi, 0, sizeof(int) * NN, stream);
    k_count<<<(NE + 255) / 256, 256, 0, stream>>>(ei, degi);
    k_scan1<<<NB_SCAN, 256, 0, stream>>>(degi, rowptr, bsum);
    k_scan2<<<1, 512, 0, stream>>>(bsum, NB_SCAN);
    k_scan3<<<NB_SCAN, 256, 0, stream>>>(rowptr, cursor, bsum);
    k_scatter<<<(NE + 255) / 256, 256, 0, stream>>>(ei, cursor, csr_src);

    // ---- GAT ----
    k_xw<<<NN, F1, 0, stream>>>(x, gat_w, att_src, att_dst, xw_bf, asr, ads);
    k_alpha<<<(NN + 3) / 4, 256, 0, stream>>>(rowptr, csr_src, asr, ads, alpha);
    k_gat_gather<<<(NN + 3) / 4, 256, 0, stream>>>(rowptr, csr_src, alpha,
                                                   (const unsigned*)xw_bf, h1);
    hipMemsetAsync(sums, 0, sizeof(float) * 256, stream);
    k_bn_stats<<<512, F1, 0, stream>>>(h1, F1, sums);
    k_bn_apply<<<(NN * F1 + 255) / 256, 256, 0, stream>>>(h1, sums, bn1_g, bn1_b, F1, NN * F1);

    // ---- SAGE: dense dual-GEMM first, then bf16 mean-gather (linearity) ----
    k_sage_dualgemm<<<NN / GROWS, 256, 0, stream>>>(h1, sage_wl, sage_wr, u_bf, vmat);
    k_sage_gather2<<<(NN + 3) / 4, 256, 0, stream>>>(rowptr, csr_src, u_bf, vmat, sage_bl, h2);
    hipMemsetAsync(sums, 0, sizeof(float) * 256, stream);
    k_bn_stats<<<512, F2, 0, stream>>>(h2, F2, sums);
    k_bn_apply<<<(NN * F2 + 255) / 256, 256, 0, stream>>>(h2, sums, bn2_g, bn2_b, F2, NN * F2);

    // ---- GCN ----
    k_dinv<<<(NN + 255) / 256, 256, 0, stream>>>(degi, dinv);
    k_gcn_gemm<<<NN / GROWS, 256, 0, stream>>>(h2, gcn_w, dinv, hwd_bf);
    k_gcn_gather<<<(NN + 3) / 4, 256, 0, stream>>>(rowptr, csr_src, hwd_bf, dinv, gcn_b, h3);
    hipMemsetAsync(sums, 0, sizeof(float) * 256, stream);
    k_bn_stats<<<512, F2, 0, stream>>>(h3, F2, sums);

    // ---- fused BN3 + ELU + pooling, then classifier ----
    hipMemsetAsync(psum, 0, sizeof(float) * NG * F2, stream);
    hipMemsetAsync(cnt, 0, sizeof(float) * NG, stream);
    k_fill_u32<<<(NG * F2 + 255) / 256, 256, 0, stream>>>(pmax, ENC_NEG_INF, NG * F2);
    k_bn3_pool<<<512, F2, 0, stream>>>(h3, sums, bn3_g, bn3_b, batch, psum, pmax, cnt);
    k_cls<<<NG, F2, 0, stream>>>(psum, pmax, cnt, w1, b1, w2, b2, out);
}